// Round 10
// baseline (159.025 us; speedup 1.0000x reference)
//
#include <hip/hip_runtime.h>

#define BATCH 2
#define CDIM 256
#define HEADS 8
#define HD 32
#define HH 56
#define WW 56
#define NQ 3136          // 56*56
#define NTOK 6272        // BATCH*NQ
#define NB 49
#define NTOPK 4
#define HID2 1024        // 2*HID
#define HIDM 512         // HID
#define QSTRH 1280       // bufQh row stride (f16): [q0|q1|q2|kw|vw]
#define ASTR 768         // Acatb row stride (bf16)

typedef short bf16x8 __attribute__((ext_vector_type(8)));
typedef float f32x4 __attribute__((ext_vector_type(4)));
typedef _Float16 h2 __attribute__((ext_vector_type(2)));
typedef _Float16 h4 __attribute__((ext_vector_type(4)));
struct __align__(16) h2x4 { h2 x, y, z, w; };

// ---------------------------------------------------------------- utilities
__device__ __forceinline__ float gelu_exact(float x) {
    return 0.5f * x * (1.f + erff(x * 0.70710678118654752f));
}

__device__ __forceinline__ short f2bf(float f) {
    union { float f; unsigned u; } v; v.f = f;
    unsigned r = v.u + 0x7FFFu + ((v.u >> 16) & 1u);
    return (short)(r >> 16);
}

__device__ __forceinline__ float fdot2h(h2 a, h2 b, float c) {
#if __has_builtin(__builtin_amdgcn_fdot2)
    return __builtin_amdgcn_fdot2(a, b, c, false);
#else
    return c + (float)a[0] * (float)b[0] + (float)a[1] * (float)b[1];
#endif
}

// async global->LDS, 16B per lane; LDS dest is wave-uniform base + lane*16
__device__ __forceinline__ void gld16(const void* gsrc, void* ldst) {
    __builtin_amdgcn_global_load_lds(
        (const __attribute__((address_space(1))) void*)gsrc,
        (__attribute__((address_space(3))) void*)ldst, 16, 0, 0);
}

// ------------------------------------------------- 0. init: NCHW->NHWC (f16) + weight convert
// blocks [0,392): transpose x -> xTh (f16); blocks [392,5010): weight convert.
// Wpin rows PERMUTED: new row p = original out-channel (p&3)*256 + (p>>2).
__global__ __launch_bounds__(256) void k_init(
        const float* __restrict__ x, _Float16* __restrict__ xTh,
        const float* __restrict__ wq_w, const float* __restrict__ wk_w,
        const float* __restrict__ wv_w, const float* __restrict__ wq_b,
        const float* __restrict__ wk_b, const float* __restrict__ wv_b,
        const float* __restrict__ pj_w, const float* __restrict__ pin_w,
        const float* __restrict__ pout_w,
        short* __restrict__ Wc1, short* __restrict__ Wpj,
        short* __restrict__ Wpin, short* __restrict__ Wpout,
        float* __restrict__ bias1, float* __restrict__ Wkv0,
        float* __restrict__ bkv0, float* __restrict__ Wkv1,
        float* __restrict__ bkv1) {
    __shared__ float t[64][65];
    int bid = blockIdx.x;
    int tid = threadIdx.x;
    if (bid < 392) {
        int p0 = (bid % 49) * 64;
        int c0 = ((bid / 49) & 3) * 64;
        int b  = bid / 196;
        int pi = tid & 63, cj = tid >> 6;
        #pragma unroll
        for (int j = 0; j < 16; j++) {
            int c = cj * 16 + j;
            t[c][pi] = x[((size_t)(b * CDIM + c0 + c)) * NQ + p0 + pi];
        }
        __syncthreads();
        int ci = tid & 63, pj = tid >> 6;
        #pragma unroll
        for (int j = 0; j < 16; j++) {
            int p = pj * 16 + j;
            xTh[((size_t)(b * NQ + p0 + p)) * CDIM + c0 + ci] = (_Float16)t[ci][p];
        }
        return;
    }
    int i = (bid - 392) * 256 + tid;
    if (i < 327680) {                       // Wc1 [1280][256]
        int r = i >> 8, k = i & 255, seg = r >> 8, n = r & 255;
        float v;
        if (seg == 0)      v = wq_w[n * 256 + k];
        else if (seg == 1) v = wq_w[65536 + n * 256 + k];
        else if (seg == 2) v = wq_w[131072 + n * 256 + k];
        else if (seg == 3) v = wk_w[131072 + n * 256 + k];
        else               v = wv_w[131072 + n * 256 + k];
        Wc1[i] = f2bf(v);
    } else if (i < 524288) {                // Wpj [256][768]
        int j = i - 327680;
        int n = j / 768, tt = j % 768, br = tt >> 8, k = tt & 255;
        Wpj[j] = f2bf(pj_w[br * 65536 + n * 256 + k]);
    } else if (i < 786432) {                // Wpin (row-permuted)
        int j = i - 524288;
        int r = j >> 8, k = j & 255;
        int o = (r & 3) * 256 + (r >> 2);
        Wpin[j] = f2bf(pin_w[o * 256 + k]);
    } else if (i < 917504) {                // Wpout
        int j = i - 786432;
        Wpout[j] = f2bf(pout_w[j]);
    } else if (i < 1048576) {               // Wkv0 fp32
        int j = i - 917504;
        int r = j >> 8, k = j & 255;
        Wkv0[j] = (r < 256) ? wk_w[r * 256 + k] : wv_w[(r - 256) * 256 + k];
    } else if (i < 1179648) {               // Wkv1 fp32
        int j = i - 1048576;
        int r = j >> 8, k = j & 255;
        Wkv1[j] = (r < 256) ? wk_w[65536 + r * 256 + k] : wv_w[65536 + (r - 256) * 256 + k];
    } else if (i < 1180928) {               // bias1
        int j = i - 1179648;
        float v;
        if (j < 768)       v = wq_b[j];
        else if (j < 1024) v = wk_b[512 + (j - 768)];
        else               v = wv_b[512 + (j - 1024)];
        bias1[j] = v;
    } else if (i < 1181440) {               // bkv0
        int j = i - 1180928;
        bkv0[j] = (j < 256) ? wk_b[j] : wv_b[j - 256];
    } else if (i < 1181952) {               // bkv1
        int j = i - 1181440;
        bkv1[j] = (j < 256) ? wk_b[256 + j] : wv_b[j];
    }
}

// ------------------------------------------------- 1b. pos conv + LN-gates (f16 input, wave/token)
__global__ __launch_bounds__(256) void k_posgates(
        const _Float16* __restrict__ xTh, const float* __restrict__ pw,
        const float* __restrict__ pb, const float* __restrict__ n1w,
        const float* __restrict__ n1b, const float* __restrict__ gw,
        const float* __restrict__ gb, float* __restrict__ feat,
        float* __restrict__ g, short* __restrict__ featb) {
    int wvid = threadIdx.x >> 6;
    int lane = threadIdx.x & 63;
    int c4 = lane * 4;
    float pwv[4][9];
    #pragma unroll
    for (int j = 0; j < 4; j++)
        #pragma unroll
        for (int i = 0; i < 9; i++) pwv[j][i] = pw[(c4 + j) * 9 + i];
    float4 pbv = *(const float4*)(pb + c4);
    float4 w1 = *(const float4*)(n1w + c4);
    float4 b1 = *(const float4*)(n1b + c4);
    float4 gw0 = *(const float4*)(gw + c4);
    float4 gw1 = *(const float4*)(gw + CDIM + c4);
    float4 gw2 = *(const float4*)(gw + 2 * CDIM + c4);
    float gb0 = gb[0], gb1 = gb[1], gb2 = gb[2];
    int tbase = blockIdx.x * 16 + wvid * 4;
    for (int t = 0; t < 4; t++) {
        int bn = tbase + t;
        int b = bn / NQ, n = bn % NQ;
        int y = n / WW, x = n % WW;
        const _Float16* xb = xTh + (size_t)b * NQ * CDIM;
        h4 a = *(const h4*)(xb + (size_t)n * CDIM + c4);
        float acc0 = (float)a[0] + pbv.x, acc1 = (float)a[1] + pbv.y;
        float acc2 = (float)a[2] + pbv.z, acc3 = (float)a[3] + pbv.w;
        #pragma unroll
        for (int dy = 0; dy < 3; dy++) {
            int yy = y + dy - 1;
            if (yy < 0 || yy >= HH) continue;
            #pragma unroll
            for (int dx = 0; dx < 3; dx++) {
                int xx = x + dx - 1;
                if (xx < 0 || xx >= WW) continue;
                h4 v = *(const h4*)(xb + ((size_t)(yy * WW + xx)) * CDIM + c4);
                int wi = dy * 3 + dx;
                acc0 += (float)v[0] * pwv[0][wi];
                acc1 += (float)v[1] * pwv[1][wi];
                acc2 += (float)v[2] * pwv[2][wi];
                acc3 += (float)v[3] * pwv[3][wi];
            }
        }
        *(float4*)(feat + (size_t)bn * CDIM + c4) = make_float4(acc0, acc1, acc2, acc3);
        short4 fb;
        fb.x = f2bf(acc0); fb.y = f2bf(acc1); fb.z = f2bf(acc2); fb.w = f2bf(acc3);
        *(short4*)(featb + (size_t)bn * CDIM + c4) = fb;
        float s = acc0 + acc1 + acc2 + acc3;
        #pragma unroll
        for (int off = 32; off > 0; off >>= 1) s += __shfl_xor(s, off);
        float mu = s * (1.f / CDIM);
        float d0 = acc0 - mu, d1 = acc1 - mu, d2 = acc2 - mu, d3 = acc3 - mu;
        float ss = d0 * d0 + d1 * d1 + d2 * d2 + d3 * d3;
        #pragma unroll
        for (int off = 32; off > 0; off >>= 1) ss += __shfl_xor(ss, off);
        float rstd = rsqrtf(ss * (1.f / CDIM) + 1e-6f);
        float q0 = d0 * rstd * w1.x + b1.x;
        float q1 = d1 * rstd * w1.y + b1.y;
        float q2 = d2 * rstd * w1.z + b1.z;
        float q3 = d3 * rstd * w1.w + b1.w;
        float p0 = q0 * gw0.x + q1 * gw0.y + q2 * gw0.z + q3 * gw0.w;
        float p1 = q0 * gw1.x + q1 * gw1.y + q2 * gw1.z + q3 * gw1.w;
        float p2 = q0 * gw2.x + q1 * gw2.y + q2 * gw2.z + q3 * gw2.w;
        #pragma unroll
        for (int off = 32; off > 0; off >>= 1) {
            p0 += __shfl_xor(p0, off);
            p1 += __shfl_xor(p1, off);
            p2 += __shfl_xor(p2, off);
        }
        if (lane == 0) {
            float l0 = p0 + gb0, l1 = p1 + gb1, l2 = p2 + gb2;
            float m3 = fmaxf(l0, fmaxf(l1, l2));
            float e0 = __expf(l0 - m3), e1 = __expf(l1 - m3), e2 = __expf(l2 - m3);
            float inv = 1.f / (e0 + e1 + e2);
            g[bn * 3 + 0] = e0 * inv;
            g[bn * 3 + 1] = e1 * inv;
            g[bn * 3 + 2] = e2 * inv;
        }
    }
}

// ------------------------------------------------- 2. block means + scores (fused)
__global__ __launch_bounds__(256) void k_blkscore(
        const float* __restrict__ feat, const float* __restrict__ s1w,
        const float* __restrict__ s1b, const float* __restrict__ s2w,
        const float* __restrict__ s2b, float* __restrict__ blk,
        float* __restrict__ scores) {
    __shared__ float sblk[256];
    __shared__ float red[128];
    int gid = blockIdx.x;
    int b = gid / NB, bid = gid % NB;
    int by = bid / 7, bx = bid % 7;
    int c = threadIdx.x;
    float s = 0.f;
    for (int iy = 0; iy < 8; iy++)
        for (int ix = 0; ix < 8; ix++) {
            int y = by * 8 + iy, xx = bx * 8 + ix;
            s += feat[((size_t)(b * NQ + y * WW + xx)) * CDIM + c];
        }
    s *= (1.f / 64.f);
    blk[(size_t)gid * CDIM + c] = s;
    sblk[c] = s;
    __syncthreads();
    if (c < 128) {
        const float* wrow = s1w + (size_t)c * CDIM;
        float acc = s1b[c];
        for (int k = 0; k < CDIM; k++) acc += sblk[k] * wrow[k];
        red[c] = gelu_exact(acc) * s2w[c];
    }
    __syncthreads();
    #pragma unroll
    for (int st = 64; st > 0; st >>= 1) {
        if (c < st) red[c] += red[c + st];
        __syncthreads();
    }
    if (c == 0) scores[gid] = red[0] + s2b[0];
}

// ------------------------------------------------- merged: QKV MFMA GEMM (XCD-swizzled) + kv fp32 GEMM
__global__ __launch_bounds__(256) void k_qkvkv(
        const short* __restrict__ A, const short* __restrict__ W,
        const float* __restrict__ bias, _Float16* __restrict__ C2,
        const float* __restrict__ blk, const float* __restrict__ Wkv0,
        const float* __restrict__ bkv0, _Float16* __restrict__ kvcmp,
        const float* __restrict__ scores, const float* __restrict__ Wkv1,
        const float* __restrict__ bkv1, _Float16* __restrict__ kvsel) {
    __shared__ __align__(16) char sm[27648];
    int bid = blockIdx.x;
    int tid = threadIdx.x;
    if (bid < 980) {
        // bijective XCD swizzle (m204): 980 = 8 chunks, q=122, r=4
        int xcd = bid & 7, idx = bid >> 3;
        int swb = (xcd < 4) ? xcd * 123 + idx : 492 + (xcd - 4) * 122 + idx;
        const int K = 256, N = 1280;
        short (*As)[72] = (short(*)[72])sm;
        short (*Bs)[72] = (short(*)[72])(sm + 64 * 72 * 2);
        int wid = tid >> 6, lane = tid & 63;
        int wm = wid >> 1, wn = wid & 1;
        int m0 = (swb / 10) * 64, n0 = (swb % 10) * 128;
        f32x4 acc[2][4] = {};
        int ar = tid >> 2, ac = (tid & 3) * 16;
        int br = tid >> 1, bc = (tid & 1) * 32;
        int fr = lane & 15, fk = (lane >> 4) * 8;
        for (int k0 = 0; k0 < K; k0 += 64) {
            const short* ap = A + (size_t)(m0 + ar) * K + k0 + ac;
            bf16x8 a0 = *(const bf16x8*)(ap);
            bf16x8 a1 = *(const bf16x8*)(ap + 8);
            const short* wp = W + (size_t)(n0 + br) * K + k0 + bc;
            bf16x8 w0 = *(const bf16x8*)(wp);
            bf16x8 w1 = *(const bf16x8*)(wp + 8);
            bf16x8 w2 = *(const bf16x8*)(wp + 16);
            bf16x8 w3 = *(const bf16x8*)(wp + 24);
            __syncthreads();
            *(bf16x8*)&As[ar][ac] = a0;
            *(bf16x8*)&As[ar][ac + 8] = a1;
            *(bf16x8*)&Bs[br][bc] = w0;
            *(bf16x8*)&Bs[br][bc + 8] = w1;
            *(bf16x8*)&Bs[br][bc + 16] = w2;
            *(bf16x8*)&Bs[br][bc + 24] = w3;
            __syncthreads();
            #pragma unroll
            for (int kk = 0; kk < 64; kk += 32) {
                bf16x8 af[2], bf[4];
                #pragma unroll
                for (int mi = 0; mi < 2; mi++)
                    af[mi] = *(const bf16x8*)&As[wm * 32 + mi * 16 + fr][kk + fk];
                #pragma unroll
                for (int ni = 0; ni < 4; ni++)
                    bf[ni] = *(const bf16x8*)&Bs[wn * 64 + ni * 16 + fr][kk + fk];
                #pragma unroll
                for (int mi = 0; mi < 2; mi++)
                    #pragma unroll
                    for (int ni = 0; ni < 4; ni++)
                        acc[mi][ni] = __builtin_amdgcn_mfma_f32_16x16x32_bf16(
                            af[mi], bf[ni], acc[mi][ni], 0, 0, 0);
            }
        }
        int rsub = (lane >> 4) * 4;
        #pragma unroll
        for (int mi = 0; mi < 2; mi++) {
            #pragma unroll
            for (int ni = 0; ni < 4; ni++) {
                int col = n0 + wn * 64 + ni * 16 + (lane & 15);
                float bv = bias[col];
                #pragma unroll
                for (int r = 0; r < 4; r++) {
                    int row = m0 + wm * 32 + mi * 16 + rsub + r;
                    C2[(size_t)row * N + col] = (_Float16)(acc[mi][ni][r] + bv);
                }
            }
        }
    } else {
        float (*As)[68] = (float(*)[68])sm;
        float (*Ws)[68] = (float(*)[68])(sm + 16 * 68 * 4);
        float (*ssc)[NB] = (float(*)[NB])(sm + 2 * 16 * 68 * 4);
        int* sidx = (int*)(sm + 2 * 16 * 68 * 4 + 2 * NB * 4);
        int kid = bid - 980;
        int kvy = kid >> 3, kvx = kid & 7;
        const float* Wk; const float* biask; _Float16* C; int M;
        int m0;
        bool sel = (kvy == 2);
        if (!sel) { Wk = Wkv0; biask = bkv0; C = kvcmp; M = 98; m0 = kvy * 64; }
        else      { Wk = Wkv1; biask = bkv1; C = kvsel; M = 8;  m0 = 0; }
        const int N = 512, K = 256;
        const int tx = tid & 15, ty = tid >> 4;
        const int n0 = kvx * 64;
        const int lr = tid >> 2;
        const int lk = (tid & 3) * 4;
        if (sel) {
            if (tid < 2 * NB) ssc[tid / NB][tid % NB] = scores[tid];
            __syncthreads();
            if (tid < 2) {
                for (int t = 0; t < NTOPK; t++) {
                    int best = 0; float bv = -1e30f;
                    for (int m = 0; m < NB; m++)
                        if (ssc[tid][m] > bv) { bv = ssc[tid][m]; best = m; }
                    sidx[tid * 4 + t] = best; ssc[tid][best] = -1e30f;
                }
            }
            __syncthreads();
        }
        int gm = m0 + lr;
        int arow = gm;
        if (sel && gm < 8) arow = (gm >> 2) * NB + sidx[gm];
        float acc[4][4] = {};
        for (int k0 = 0; k0 < K; k0 += 16) {
            float4 av = make_float4(0.f, 0.f, 0.f, 0.f);
            if (gm < M) av = *(const float4*)(blk + (size_t)arow * K + k0 + lk);
            int gn = n0 + lr;
            float4 wv = *(const float4*)(Wk + (size_t)gn * K + k0 + lk);
            __syncthreads();
            As[lk][lr] = av.x; As[lk + 1][lr] = av.y; As[lk + 2][lr] = av.z; As[lk + 3][lr] = av.w;
            Ws[lk][lr] = wv.x; Ws[lk + 1][lr] = wv.y; Ws[lk + 2][lr] = wv.z; Ws[lk + 3][lr] = wv.w;
            __syncthreads();
            #pragma unroll
            for (int kk = 0; kk < 16; kk++) {
                const float4 a = *(const float4*)&As[kk][ty * 4];
                const float4 b = *(const float4*)&Ws[kk][tx * 4];
                acc[0][0] += a.x * b.x; acc[0][1] += a.x * b.y; acc[0][2] += a.x * b.z; acc[0][3] += a.x * b.w;
                acc[1][0] += a.y * b.x; acc[1][1] += a.y * b.y; acc[1][2] += a.y * b.z; acc[1][3] += a.y * b.w;
                acc[2][0] += a.z * b.x; acc[2][1] += a.z * b.y; acc[2][2] += a.z * b.z; acc[2][3] += a.z * b.w;
                acc[3][0] += a.w * b.x; acc[3][1] += a.w * b.y; acc[3][2] += a.w * b.z; acc[3][3] += a.w * b.w;
            }
        }
        #pragma unroll
        for (int i = 0; i < 4; i++) {
            int om = m0 + ty * 4 + i;
            if (om >= M) break;
            #pragma unroll
            for (int j = 0; j < 4; j++) {
                int gn = n0 + tx * 4 + j;
                C[(size_t)om * N + gn] = (_Float16)(acc[i][j] + biask[gn]);
            }
        }
    }
}

// ------------------------------------------------- MFMA GEMM 64x128, BK=64, XCD-swizzled, f16 out
__global__ __launch_bounds__(256) void k_gemm64x128(
        const short* __restrict__ A, const short* __restrict__ W,
        const float* __restrict__ bias, int M, int N, int K,
        _Float16* __restrict__ C2) {
    __shared__ short As[64][72];
    __shared__ short Bs[128][72];
    int tid = threadIdx.x;
    int wid = tid >> 6, lane = tid & 63;
    int wm = wid >> 1, wn = wid & 1;
    int lin = blockIdx.y * gridDim.x + blockIdx.x;
    int cpx = (gridDim.x * gridDim.y) >> 3;          // grid total divisible by 8
    int swz = (lin & 7) * cpx + (lin >> 3);
    int m0 = (swz / gridDim.x) * 64, n0 = (swz % gridDim.x) * 128;
    f32x4 acc[2][4] = {};
    int ar = tid >> 2, ac = (tid & 3) * 16;
    int br = tid >> 1, bc = (tid & 1) * 32;
    int fr = lane & 15, fk = (lane >> 4) * 8;
    for (int k0 = 0; k0 < K; k0 += 64) {
        const short* ap = A + (size_t)(m0 + ar) * K + k0 + ac;
        bf16x8 a0 = *(const bf16x8*)(ap);
        bf16x8 a1 = *(const bf16x8*)(ap + 8);
        const short* wp = W + (size_t)(n0 + br) * K + k0 + bc;
        bf16x8 w0 = *(const bf16x8*)(wp);
        bf16x8 w1 = *(const bf16x8*)(wp + 8);
        bf16x8 w2 = *(const bf16x8*)(wp + 16);
        bf16x8 w3 = *(const bf16x8*)(wp + 24);
        __syncthreads();
        *(bf16x8*)&As[ar][ac] = a0;
        *(bf16x8*)&As[ar][ac + 8] = a1;
        *(bf16x8*)&Bs[br][bc] = w0;
        *(bf16x8*)&Bs[br][bc + 8] = w1;
        *(bf16x8*)&Bs[br][bc + 16] = w2;
        *(bf16x8*)&Bs[br][bc + 24] = w3;
        __syncthreads();
        #pragma unroll
        for (int kk = 0; kk < 64; kk += 32) {
            bf16x8 af[2], bf[4];
            #pragma unroll
            for (int mi = 0; mi < 2; mi++)
                af[mi] = *(const bf16x8*)&As[wm * 32 + mi * 16 + fr][kk + fk];
            #pragma unroll
            for (int ni = 0; ni < 4; ni++)
                bf[ni] = *(const bf16x8*)&Bs[wn * 64 + ni * 16 + fr][kk + fk];
            #pragma unroll
            for (int mi = 0; mi < 2; mi++)
                #pragma unroll
                for (int ni = 0; ni < 4; ni++)
                    acc[mi][ni] = __builtin_amdgcn_mfma_f32_16x16x32_bf16(
                        af[mi], bf[ni], acc[mi][ni], 0, 0, 0);
        }
    }
    int rsub = (lane >> 4) * 4;
    #pragma unroll
    for (int mi = 0; mi < 2; mi++) {
        #pragma unroll
        for (int ni = 0; ni < 4; ni++) {
            int col = n0 + wn * 64 + ni * 16 + (lane & 15);
            float bv = bias ? bias[col] : 0.f;
            #pragma unroll
            for (int r = 0; r < 4; r++) {
                int row = m0 + wm * 32 + mi * 16 + rsub + r;
                C2[(size_t)row * N + col] = (_Float16)(acc[mi][ni][r] + bv);
            }
        }
    }
}

// ------------------------------------------------- MFMA GEMM 64x64, BK=64, XCD-swizzled (resid epi)
__global__ __launch_bounds__(256) void k_gemm64(
        const short* __restrict__ A, const short* __restrict__ W,
        const float* __restrict__ bias, float* __restrict__ C,
        int M, int N, int K,
        const float* __restrict__ resid, const float* __restrict__ g3,
        const float* __restrict__ pjb, short* __restrict__ Cb) {
    __shared__ short As[64][72];
    __shared__ short Bs[64][72];
    int tid = threadIdx.x;
    int wid = tid >> 6, lane = tid & 63;
    int wm = wid >> 1, wn = wid & 1;
    int lin = blockIdx.y * gridDim.x + blockIdx.x;
    int cpx = (gridDim.x * gridDim.y) >> 3;
    int swz = (lin & 7) * cpx + (lin >> 3);
    int m0 = (swz / gridDim.x) * 64, n0 = (swz % gridDim.x) * 64;
    f32x4 acc[2][2] = {};
    int ar = tid >> 2, ac = (tid & 3) * 16;
    int fr = lane & 15, fk = (lane >> 4) * 8;
    for (int k0 = 0; k0 < K; k0 += 64) {
        const short* ap = A + (size_t)(m0 + ar) * K + k0 + ac;
        bf16x8 a0 = *(const bf16x8*)(ap);
        bf16x8 a1 = *(const bf16x8*)(ap + 8);
        const short* wp = W + (size_t)(n0 + ar) * K + k0 + ac;
        bf16x8 w0 = *(const bf16x8*)(wp);
        bf16x8 w1 = *(const bf16x8*)(wp + 8);
        __syncthreads();
        *(bf16x8*)&As[ar][ac] = a0;
        *(bf16x8*)&As[ar][ac + 8] = a1;
        *(bf16x8*)&Bs[ar][ac] = w0;
        *(bf16x8*)&Bs[ar][ac + 8] = w1;
        __syncthreads();
        #pragma unroll
        for (int kk = 0; kk < 64; kk += 32) {
            bf16x8 af[2], bf[2];
            #pragma unroll
            for (int mi = 0; mi < 2; mi++)
                af[mi] = *(const bf16x8*)&As[wm * 32 + mi * 16 + fr][kk + fk];
            #pragma unroll
            for (int ni = 0; ni < 2; ni++)
                bf[ni] = *(const bf16x8*)&Bs[wn * 32 + ni * 16 + fr][kk + fk];
            #pragma unroll
            for (int mi = 0; mi < 2; mi++)
                #pragma unroll
                for (int ni = 0; ni < 2; ni++)
                    acc[mi][ni] = __builtin_amdgcn_mfma_f32_16x16x32_bf16(
                        af[mi], bf[ni], acc[mi][ni], 0, 0, 0);
        }
    }
    int rsub = (lane >> 4) * 4;
    #pragma unroll
    for (int mi = 0; mi < 2; mi++) {
        #pragma unroll
        for (int ni = 0; ni < 2; ni++) {
            int col = n0 + wn * 32 + ni * 16 + (lane & 15);
            #pragma unroll
            for (int r = 0; r < 4; r++) {
                int row = m0 + wm * 32 + mi * 16 + rsub + r;
                float v = acc[mi][ni][r];
                if (resid) {
                    v += resid[(size_t)row * N + col]
                       + g3[row * 3 + 0] * pjb[col]
                       + g3[row * 3 + 1] * pjb[256 + col]
                       + g3[row * 3 + 2] * pjb[512 + col];
                } else if (bias) {
                    v += bias[col];
                }
                C[(size_t)row * N + col] = v;
                if (Cb) Cb[(size_t)row * N + col] = f2bf(v);
            }
        }
    }
}

// ------------------------------------------------- pout GEMM + final LN + NCHW write (fused)
__global__ __launch_bounds__(256) void k_poutln(
        const short* __restrict__ G, const short* __restrict__ W,
        const float* __restrict__ ym, const float* __restrict__ n2w,
        const float* __restrict__ n2b, float* __restrict__ out) {
    __shared__ short As[32][72];
    __shared__ float redS[4][36];
    __shared__ float redQ[4][36];
    int tid = threadIdx.x;
    int wid = tid >> 6, lane = tid & 63;
    int bx = blockIdx.x;
    int b = bx / 98;
    int t0g = bx * 32;                 // global token base
    int p0 = (bx % 98) * 32;           // pixel base within batch
    f32x4 acc[2][4] = {};
    int ar = tid >> 3, ac = (tid & 7) * 8;
    int fr = lane & 15, fk = (lane >> 4) * 8;
    const short* Wb = W + (size_t)(wid * 64) * 512;
    for (int k0 = 0; k0 < 512; k0 += 64) {
        bf16x8 a0 = *(const bf16x8*)(G + (size_t)(t0g + ar) * 512 + k0 + ac);
        __syncthreads();
        *(bf16x8*)&As[ar][ac] = a0;
        __syncthreads();
        #pragma unroll
        for (int kk = 0; kk < 64; kk += 32) {
            bf16x8 af[2], bf[4];
            #pragma unroll
            for (int mi = 0; mi < 2; mi++)
                af[mi] = *(const bf16x8*)&As[mi * 16 + fr][kk + fk];
            #pragma unroll
            for (int ni = 0; ni < 4; ni++)
                bf[ni] = *(const bf16x8*)(Wb + (size_t)(ni * 16 + fr) * 512 + k0 + kk + fk);
            #pragma unroll
            for (int mi = 0; mi < 2; mi++)
                #pragma unroll
                for (int ni = 0; ni < 4; ni++)
                    acc[mi][ni] = __builtin_amdgcn_mfma_f32_16x16x32_bf16(
                        af[mi], bf[ni], acc[mi][ni], 0, 0, 0);
        }
    }
    int rsub = (lane >> 4) * 4;
    float v[2][4][4];
    #pragma unroll
    for (int mi = 0; mi < 2; mi++)
        #pragma unroll
        for (int ni = 0; ni < 4; ni++) {
            int col = wid * 64 + ni * 16 + fr;
            #pragma unroll
            for (int r = 0; r < 4; r++) {
                int row = mi * 16 + rsub + r;
                v[mi][ni][r] = acc[mi][ni][r] + ym[(size_t)(t0g + row) * CDIM + col];
            }
        }
    #pragma unroll
    for (int mi = 0; mi < 2; mi++) {
        #pragma unroll
        for (int r = 0; r < 4; r++) {
            float s = v[mi][0][r] + v[mi][1][r] + v[mi][2][r] + v[mi][3][r];
            s += __shfl_xor(s, 1); s += __shfl_xor(s, 2);
            s += __shfl_xor(s, 4); s += __shfl_xor(s, 8);
            if (fr == 0) redS[wid][mi * 16 + rsub + r] = s;
        }
    }
    __syncthreads();
    float mu[2][4];
    #pragma unroll
    for (int mi = 0; mi < 2; mi++)
        #pragma unroll
        for (int r = 0; r < 4; r++) {
            int row = mi * 16 + rsub + r;
            mu[mi][r] = (redS[0][row] + redS[1][row] + redS[2][row] + redS[3][row])
                        * (1.f / CDIM);
        }
    #pragma unroll
    for (int mi = 0; mi < 2; mi++) {
        #pragma unroll
        for (int r = 0; r < 4; r++) {
            float m = mu[mi][r];
            float d0 = v[mi][0][r] - m, d1 = v[mi][1][r] - m;
            float d2 = v[mi][2][r] - m, d3 = v[mi][3][r] - m;
            float q = d0 * d0 + d1 * d1 + d2 * d2 + d3 * d3;
            q += __shfl_xor(q, 1); q += __shfl_xor(q, 2);
            q += __shfl_xor(q, 4); q += __shfl_xor(q, 8);
            if (fr == 0) redQ[wid][mi * 16 + rsub + r] = q;
        }
    }
    __syncthreads();
    float rstd[2][4];
    #pragma unroll
    for (int mi = 0; mi < 2; mi++)
        #pragma unroll
        for (int r = 0; r < 4; r++) {
            int row = mi * 16 + rsub + r;
            float var = (redQ[0][row] + redQ[1][row] + redQ[2][row] + redQ[3][row])
                        * (1.f / CDIM);
            rstd[mi][r] = rsqrtf(var + 1e-6f);
        }
    #pragma unroll
    for (int mi = 0; mi < 2; mi++) {
        #pragma unroll
        for (int ni = 0; ni < 4; ni++) {
            int col = wid * 64 + ni * 16 + fr;
            float wgt = n2w[col], bia = n2b[col];
            float4 o;
            o.x = (v[mi][ni][0] - mu[mi][0]) * rstd[mi][0] * wgt + bia;
            o.y = (v[mi][ni][1] - mu[mi][1]) * rstd[mi][1] * wgt + bia;
            o.z = (v[mi][ni][2] - mu[mi][2]) * rstd[mi][2] * wgt + bia;
            o.w = (v[mi][ni][3] - mu[mi][3]) * rstd[mi][3] * wgt + bia;
            *(float4*)(out + ((size_t)(b * CDIM + col)) * NQ + p0 + mi * 16 + rsub) = o;
        }
    }
}

// ------------------------------------------------- fused attention, f16 LDS-staged K/V
// 512 threads, 16 tokens/block.  blocks [0,392): cmp+sel (16 linear tokens);
// [392,784): window (4x4 token tile, 10x10 px union).
__global__ __launch_bounds__(512) void k_attn_lds(
        const _Float16* __restrict__ bufQ, const _Float16* __restrict__ kvc,
        const _Float16* __restrict__ kvs, short* __restrict__ Acatb,
        const float* __restrict__ g) {
    __shared__ uint4 buf[100 * 32];       // 51.2 KB
    int tid = threadIdx.x;
    int wid = tid >> 6;                   // 0..7
    int lane = tid & 63;
    int l = tid & 31;                     // lane within token group
    int tk = tid >> 5;                    // token 0..15 within block
    int dg = l & 3;
    int co = l * 8;                       // channel offset
    const float scale = 0.17677669529663687f;

    if (blockIdx.x < 392) {
        // ======================= cmp + sel =======================
        int bid = blockIdx.x;
        int swz = (bid & 7) * 49 + (bid >> 3);    // bijective XCD swizzle (392=8*49)
        int t0 = swz * 16;
        int tok = t0 + tk;
        int b = t0 / NQ;
        const _Float16* kb = kvc + (size_t)b * NB * 512;
        for (int p = wid * 2; p < NB + 1; p += 16) {
            int myp = p + (lane >> 5);
            if (myp > NB - 1) myp = NB - 1;
            gld16((const uint4*)(kb + (size_t)myp * 512) + (lane & 31), &buf[p * 32]);
        }
        const _Float16* qrow = bufQ + (size_t)tok * QSTRH;
        float gate0 = g[tok * 3 + 0];
        float gate1 = g[tok * 3 + 1];
        short* orow = Acatb + (size_t)tok * ASTR;
        h2x4 qv = *(const h2x4*)(qrow + co);
        __syncthreads();                  // K staged
        float sc[13];
        sc[12] = -1e30f;
        #pragma unroll
        for (int m = 0; m < NB; m++) {
            h2x4 kv = *(const h2x4*)&buf[m * 32 + l];
            float acc = fdot2h(qv.x, kv.x, 0.f);
            acc = fdot2h(qv.y, kv.y, acc);
            acc = fdot2h(qv.z, kv.z, acc);
            acc = fdot2h(qv.w, kv.w, acc);
            acc += __shfl_xor(acc, 1);
            acc += __shfl_xor(acc, 2);
            if ((m & 3) == dg) sc[m >> 2] = acc * scale;
        }
        float mx = sc[0];
        #pragma unroll
        for (int i = 1; i < 13; i++) mx = fmaxf(mx, sc[i]);
        mx = fmaxf(mx, __shfl_xor(mx, 1));
        mx = fmaxf(mx, __shfl_xor(mx, 2));
        float sum = 0.f;
        #pragma unroll
        for (int i = 0; i < 13; i++) { sc[i] = __expf(sc[i] - mx); sum += sc[i]; }
        sum += __shfl_xor(sum, 1);
        sum += __shfl_xor(sum, 2);
        float inv_c = 1.f / sum;
        __syncthreads();                  // all waves done reading K
        for (int p = wid * 2; p < NB + 1; p += 16) {
            int myp = p + (lane >> 5);
            if (myp > NB - 1) myp = NB - 1;
            gld16((const uint4*)(kb + (size_t)myp * 512 + 256) + (lane & 31), &buf[p * 32]);
        }
        {
            const _Float16* ksb = kvs + (size_t)b * NTOPK * 512;
            h2x4 qs = *(const h2x4*)(qrow + 256 + co);
            float sv = 0.f;
            #pragma unroll
            for (int m = 0; m < NTOPK; m++) {
                h2x4 kk = *(const h2x4*)(ksb + (size_t)m * 512 + co);
                float acc = fdot2h(qs.x, kk.x, 0.f);
                acc = fdot2h(qs.y, kk.y, acc);
                acc = fdot2h(qs.z, kk.z, acc);
                acc = fdot2h(qs.w, kk.w, acc);
                acc += __shfl_xor(acc, 1);
                acc += __shfl_xor(acc, 2);
                if (m == dg) sv = acc * scale;
            }
            float mxs = sv;
            mxs = fmaxf(mxs, __shfl_xor(mxs, 1));
            mxs = fmaxf(mxs, __shfl_xor(mxs, 2));
            float e = __expf(sv - mxs);
            float sums = e;
            sums += __shfl_xor(sums, 1);
            sums += __shfl_xor(sums, 2);
            float invs = 1.f / sums;
            float o[8];
            #pragma unroll
            for (int d = 0; d < 8; d++) o[d] = 0.f;
            #pragma unroll
            for (int m = 0; m < NTOPK; m++) {
                float pw = __shfl(e, m, 4);
                h2x4 vv = *(const h2x4*)(ksb + (size_t)m * 512 + 256 + co);
                o[0] += pw * (float)vv.x[0]; o[1] += pw * (float)vv.x[1];
                o[2] += pw * (float)vv.y[0]; o[3] += pw * (float)vv.y[1];
                o[4] += pw * (float)vv.z[0]; o[5] += pw * (float)vv.z[1];
                o[6] += pw * (float)vv.w[0]; o[7] += pw * (float)vv.w[1];
            }
            float gg = gate1 * invs;
            bf16x8 ov;
            #pragma unroll
            for (int d = 0; d < 8; d++) ov[d] = f2bf(o[d] * gg);
            *(bf16x8*)(orow + 256 + co) = ov;
        }
        __syncthreads();                  // V staged
        {
            float o[8];
            #pragma unroll
            for (int d = 0; d < 8; d++) o[d] = 0.f;
            #pragma unroll
            for (int m = 0; m < NB; m++) {
                float pw = __shfl(sc[m >> 2], m & 3, 4);
                h2x4 vv = *(const h2x4*)&buf[m * 32 + l];
                o[0] += pw * (float)vv.x[0]; o[1] += pw * (float)vv.x[1];
                o[2] += pw * (float)vv.y[0]; o[3] += pw * (float)vv.y[1];
                o[4] += pw * (float)vv.z[0]; o[5] += pw * (float)vv.z[1];
                o[6] += pw * (float)vv.w[0]; o[7] += pw * (float)vv.w[1];
            }
            float gg = gate0 * inv_c;
            bf16x8 ov;
            #pragma unroll
            for (int d = 0; d < 8; d++) ov[d] = f2bf(o[d] * gg);
            *(bf16x8*)(orow + co) = ov;
        }
    } else {
        // ======================= window (4x4 tile) =======================
        int bid = blockIdx.x - 392;
        int swz = (bid & 7) * 49 + (bid >> 3);
        int b = swz / 196;
        int r = swz % 196;
        int y0 = (r / 14) * 4;
        int x0 = (r % 14) * 4;
        int ty = tk >> 2, tx = tk & 3;
        int y = y0 + ty, x = x0 + tx;
        int tok = b * NQ + y * WW + x;
        const _Float16* KVb = bufQ + (size_t)b * NQ * QSTRH;
        for (int p = wid * 2; p < 100; p += 16) {
            int pp = p + (lane >> 5);
            int pr = pp / 10, pc = pp - pr * 10;
            int gy = min(max(y0 + pr - 3, 0), HH - 1);
            int gx = min(max(x0 + pc - 3, 0), WW - 1);
            gld16((const uint4*)(KVb + (size_t)(gy * WW + gx) * QSTRH + 768) + (lane & 31),
                  &buf[p * 32]);
        }
        h2x4 qv = *(const h2x4*)(bufQ + (size_t)tok * QSTRH + 512 + co);
        float gate = g[tok * 3 + 2];
        __syncthreads();                  // K staged
        float sw[13];
        sw[12] = -1e30f;
        #pragma unroll
        for (int dy = 0; dy < 7; dy++) {
            #pragma unroll
            for (int dx = 0; dx < 7; dx++) {
                int p = (ty + dy) * 10 + tx + dx;
                h2x4 kv = *(const h2x4*)&buf[p * 32 + l];
                float acc = fdot2h(qv.x, kv.x, 0.f);
                acc = fdot2h(qv.y, kv.y, acc);
                acc = fdot2h(qv.z, kv.z, acc);
                acc = fdot2h(qv.w, kv.w, acc);
                acc += __shfl_xor(acc, 1);
                acc += __shfl_xor(acc, 2);
                int m = dy * 7 + dx;
                if ((m & 3) == dg) sw[m >> 2] = acc * scale;
            }
        }
        float mx = sw[0];
        #pragma unroll
        for (int i = 1; i < 13; i++) mx = fmaxf(mx, sw[i]);
        mx = fmaxf(mx, __shfl_xor(mx, 1));
        mx = fmaxf(mx, __shfl_xor(mx, 2));
        float sum = 0.f;
        #pragma unroll
        for (int i = 0; i < 13; i++) { sw[i] = __expf(sw[i] - mx); sum += sw[i]; }
        sum += __shfl_xor(sum, 1);
        sum += __shfl_xor(sum, 2);
        float inv = 1.f / sum;
        __syncthreads();                  // all waves done reading K
        for (int p = wid * 2; p < 100; p += 16) {
            int pp = p + (lane >> 5);
            int pr = pp / 10, pc = pp - pr * 10;
            int gy = min(max(y0 + pr - 3, 0), HH - 1);
            int gx = min(max(x0 + pc - 3, 0), WW - 1);
            gld16((const uint4*)(KVb + (size_t)(gy * WW + gx) * QSTRH + 1024) + (lane & 31),
                  &buf[p * 32]);
        }
        __syncthreads();                  // V staged
        float o[8];
        #pragma unroll
        for (int d = 0; d < 8; d++) o[d] = 0.f;
        #pragma unroll
        for (int dy = 0; dy < 7; dy++) {
            #pragma unroll
            for (int dx = 0; dx < 7; dx++) {
                int p = (ty + dy) * 10 + tx + dx;
                int m = dy * 7 + dx;
                float pw = __shfl(sw[m >> 2], m & 3, 4);
                h2x4 vv = *(const h2x4*)&buf[p * 32 + l];
                o[0] += pw * (float)vv.x[0]; o[1] += pw * (float)vv.x[1];
                o[2] += pw * (float)vv.y[0]; o[3] += pw * (float)vv.y[1];
                o[4] += pw * (float)vv.z[0]; o[5] += pw * (float)vv.z[1];
                o[6] += pw * (float)vv.w[0]; o[7] += pw * (float)vv.w[1];
            }
        }
        float gg = gate * inv;
        short* op = Acatb + (size_t)tok * ASTR + 512 + co;
        bf16x8 ov;
        #pragma unroll
        for (int d = 0; d < 8; d++) ov[d] = f2bf(o[d] * gg);
        *(bf16x8*)(op) = ov;
    }
}

// ------------------------------------------------- dwconv 3x3 + GLU (2 y-rows/block, h4 loads)
__global__ __launch_bounds__(256) void k_dwglu2(
        const _Float16* __restrict__ t, const float* __restrict__ w,
        short* __restrict__ G) {
    int gid = blockIdx.x;
    int xq = gid & 7;                 // 8 chunks of 7 pixels
    int y0 = ((gid >> 3) % (HH / 2)) * 2;
    int b = gid / ((HH / 2) * 8);
    int c = threadIdx.x;
    float wv[9][4];
    #pragma unroll
    for (int i = 0; i < 9; i++)
        #pragma unroll
        for (int j = 0; j < 4; j++) wv[i][j] = w[i * HID2 + j * 256 + c];
    const _Float16* tb = t + (size_t)b * NQ * HID2;
    short* Gbase = G + (size_t)b * NQ * HIDM;
    int x0 = xq * 7;
    float col[3][4][4];               // [xslot][row y0-1..y0+2][j]
    #pragma unroll
    for (int ci = 0; ci < 2; ci++) {
        int xx = x0 - 1 + ci;
        #pragma unroll
        for (int r = 0; r < 4; r++) {
            int yy = y0 + r - 1;
            bool ok = (xx >= 0) && (yy >= 0) && (yy < HH);
            h4 v = {};
            if (ok) v = *(const h4*)(tb + ((size_t)(yy * WW + xx)) * HID2 + c * 4);
            #pragma unroll
            for (int j = 0; j < 4; j++) col[ci][r][j] = (float)v[j];
        }
    }
    #pragma unroll
    for (int i = 0; i < 7; i++) {
        int xx = x0 + i;
        {
            int xl = xx + 1;
            #pragma unroll
            for (int r = 0; r < 4; r++) {
                int yy = y0 + r - 1;
                bool ok = (xl < WW) && (yy >= 0) && (yy < HH);
                h4 v = {};
                if (ok) v = *(const h4*)(tb + ((size_t)(yy * WW + xl)) * HID2 + c * 4);
                #pragma unroll
                for (int j = 0; j < 4; j++) col[(i + 2) % 3][r][j] = (float)v[j];
            }
        }
        #pragma unroll
        for (int o = 0; o < 2; o++) {
            float a0 = 0.f, a1 = 0.f, a2 = 0.f, a3 = 0.f;
            #pragma unroll
            for (int r = 0; r < 3; r++) {
                #pragma unroll
                for (int dxx = 0; dxx < 3; dxx++) {
                    const float* cc = col[(i + dxx) % 3][r + o];
                    int wi = r * 3 + dxx;
                    a0 += cc[0] * wv[wi][0];
                    a1 += cc[1] * wv[wi][1];
                    a2 += cc[2] * wv[wi][2];
                    a3 += cc[3] * wv[wi][3];
                }
            }
            short* Gb = Gbase + (size_t)((y0 + o) * WW + xx) * HIDM;
            Gb[c]       = f2bf(gelu_exact(a0) * a2);
            Gb[c + 256] = f2bf(gelu_exact(a1) * a3);
        }
    }
}

// ================================================================ host
extern "C" void kernel_launch(void* const* d_in, const int* in_sizes, int n_in,
                              void* d_out, int out_size, void* d_ws, size_t ws_size,
                              hipStream_t stream) {
    const float* x     = (const float*)d_in[0];
    const float* pos_w = (const float*)d_in[1];
    const float* pos_b = (const float*)d_in[2];
    const float* n1w   = (const float*)d_in[3];
    const float* n1b   = (const float*)d_in[4];
    const float* n2w   = (const float*)d_in[5];
    const float* n2b   = (const float*)d_in[6];
    const float* wq_w  = (const float*)d_in[7];
    const float* wq_b  = (const float*)d_in[8];
    const float* wk_w  = (const float*)d_in[9];
    const float* wk_b  = (const float*)d_in[10];
    const float* wv_w  = (const float*)d_in[11];
    const float* wv_b  = (const float*)d_in[12];
    const float* pj_w  = (const float*)d_in[13];
    const float* pj_b  = (const float*)d_in[14];
    const float* s1w   = (const float*)d_in[15];
    const float* s1b   = (const float*)d_in[16];
    const float* s2w   = (const float*)d_in[17];
    const float* s2b   = (const float*)d_in[18];
    const float* gw    = (const float*)d_in[19];
    const float* gb    = (const float*)d_in[20];
    const float* pinw  = (const float*)d_in[21];
    const float* dww   = (const float*)d_in[22];
    const float* poutw = (const float*)d_in[23];
    float* out = (float*)d_out;
    float* ws  = (float*)d_ws;

    const size_t SZ = (size_t)NTOK * CDIM;
    float* feat = ws;                               // [NTOK,256] fp32
    _Float16* bufQh = (_Float16*)(feat + SZ);       // [NTOK,1280] f16 (q0|q1|q2|kw|vw)
    float* R1   = (float*)(bufQh + (size_t)NTOK * QSTRH);  // xTh / Acatb / T1h share
    _Float16* xTh = (_Float16*)R1;                  // [NTOK,256] f16
    short* Acatb = (short*)R1;                      // [NTOK,768] bf16
    _Float16* T1h = (_Float16*)R1;                  // [NTOK,1024] f16 (permuted channels)
    float* ym   = R1 + (size_t)NTOK * 512;          // [NTOK,256] fp32
    short* featb = (short*)(ym + SZ);               // [NTOK,256] bf16
    short* ymb   = featb + (size_t)NTOK * CDIM;     // [NTOK,256] bf16
    float* blk   = (float*)(ymb + (size_t)NTOK * CDIM);  // [98,256] fp32
    _Float16* kvcmp = (_Float16*)(blk + 98 * 256);  // [98,512] f16
    _Float16* kvsel = kvcmp + 98 * 512;             // [8,512] f16
    float* scores = (float*)(kvsel + 8 * 512);      // [128]
    float* g      = scores + 128;                   // [NTOK,3]
    float* bias1  = g + (size_t)NTOK * 3;           // [1280]
    float* Wkv0   = bias1 + 1280;                   // [512,256] fp32
    float* bkv0   = Wkv0 + 512 * 256;
    float* Wkv1   = bkv0 + 512;
    float* bkv1   = Wkv1 + 512 * 256;
    short* Wc1    = (short*)(bkv1 + 512);           // bf16 [1280,256]
    short* Wpj    = Wc1 + 1280 * 256;               // bf16 [256,768]
    short* Wpin   = Wpj + 256 * 768;                // bf16 [1024,256] (row-permuted)
    short* Wpout  = Wpin + 1024 * 256;              // bf16 [256,512]
    short* G      = (short*)bufQh;                  // alias [NTOK,512] bf16 (bufQh dead after attn)

    // merged transpose (f16) + weight convert (independent work, one launch)
    hipLaunchKernelGGL(k_init, dim3(392 + 4618), dim3(256), 0, stream,
                       x, xTh, wq_w, wk_w, wv_w, wq_b, wk_b, wv_b, pj_w, pinw, poutw,
                       Wc1, Wpj, Wpin, Wpout, bias1, Wkv0, bkv0, Wkv1, bkv1);
    hipLaunchKernelGGL(k_posgates, dim3(NTOK / 16), dim3(256), 0, stream,
                       xTh, pos_w, pos_b, n1w, n1b, gw, gb, feat, g, featb);
    hipLaunchKernelGGL(k_blkscore, dim3(BATCH * NB), dim3(256), 0, stream,
                       feat, s1w, s1b, s2w, s2b, blk, scores);
    // merged QKV projection (980 blocks, XCD-swizzled) + kvcmp/kvsel fp32 GEMM (24 blocks)
    hipLaunchKernelGGL(k_qkvkv, dim3(1004), dim3(256), 0, stream,
                       featb, Wc1, bias1, bufQh,
                       blk, Wkv0, bkv0, kvcmp, scores, Wkv1, bkv1, kvsel);
    // all attention branches (16 tokens/block, f16 LDS-staged K/V) -> gated Acatb (bf16)
    hipLaunchKernelGGL(k_attn_lds, dim3(784), dim3(512), 0, stream,
                       bufQh, kvcmp, kvsel, Acatb, g);
    // fused output projection + residual + gated biases -> ym fp32 + ymb bf16  (392 blocks)
    hipLaunchKernelGGL(k_gemm64, dim3(CDIM / 64, NTOK / 64), dim3(256), 0, stream,
                       Acatb, Wpj, nullptr, ym, NTOK, CDIM, ASTR, feat, g, pj_b, ymb);
    // DBFFN: pin (row-permuted W) -> T1h f16 (channel-interleaved)  (784 blocks)
    hipLaunchKernelGGL(k_gemm64x128, dim3(HID2 / 128, NTOK / 64), dim3(256), 0, stream,
                       ymb, Wpin, nullptr, NTOK, HID2, 256, T1h);
    hipLaunchKernelGGL(k_dwglu2, dim3(BATCH * (HH / 2) * 8), dim3(256), 0, stream, T1h, dww, G);
    // fused pout GEMM + final LN + NCHW write
    hipLaunchKernelGGL(k_poutln, dim3(NTOK / 32), dim3(256), 0, stream,
                       G, Wpout, ym, n2w, n2b, out);
}

// Round 11
// 157.393 us; speedup vs baseline: 1.0104x; 1.0104x over previous
//
#include <hip/hip_runtime.h>

#define BATCH 2
#define CDIM 256
#define HEADS 8
#define HD 32
#define HH 56
#define WW 56
#define NQ 3136          // 56*56
#define NTOK 6272        // BATCH*NQ
#define NB 49
#define NTOPK 4
#define HID2 1024        // 2*HID
#define HIDM 512         // HID
#define QSTRH 1280       // bufQh row stride (f16): [q0|q1|q2|kw|vw]
#define ASTR 768         // Acatb row stride (bf16)

typedef short bf16x8 __attribute__((ext_vector_type(8)));
typedef float f32x4 __attribute__((ext_vector_type(4)));
typedef _Float16 h2 __attribute__((ext_vector_type(2)));
typedef _Float16 h4 __attribute__((ext_vector_type(4)));
struct __align__(16) h2x4 { h2 x, y, z, w; };

// ---------------------------------------------------------------- utilities
__device__ __forceinline__ float gelu_exact(float x) {
    return 0.5f * x * (1.f + erff(x * 0.70710678118654752f));
}

__device__ __forceinline__ short f2bf(float f) {
    union { float f; unsigned u; } v; v.f = f;
    unsigned r = v.u + 0x7FFFu + ((v.u >> 16) & 1u);
    return (short)(r >> 16);
}

__device__ __forceinline__ float fdot2h(h2 a, h2 b, float c) {
#if __has_builtin(__builtin_amdgcn_fdot2)
    return __builtin_amdgcn_fdot2(a, b, c, false);
#else
    return c + (float)a[0] * (float)b[0] + (float)a[1] * (float)b[1];
#endif
}

// async global->LDS, 16B per lane; LDS dest is wave-uniform base + lane*16
__device__ __forceinline__ void gld16(const void* gsrc, void* ldst) {
    __builtin_amdgcn_global_load_lds(
        (const __attribute__((address_space(1))) void*)gsrc,
        (__attribute__((address_space(3))) void*)ldst, 16, 0, 0);
}

// ------------------------------------------------- 0. init: NCHW->NHWC transpose + weight convert (merged)
// blocks [0,392): transpose x -> xT; blocks [392,5010): weight convert.
// Wpin rows are PERMUTED: new row p holds original out-channel
// (p&3)*256 + (p>>2) (enables 8B h4 loads in k_dwglu2).
__global__ __launch_bounds__(256) void k_init(
        const float* __restrict__ x, float* __restrict__ xT,
        const float* __restrict__ wq_w, const float* __restrict__ wk_w,
        const float* __restrict__ wv_w, const float* __restrict__ wq_b,
        const float* __restrict__ wk_b, const float* __restrict__ wv_b,
        const float* __restrict__ pj_w, const float* __restrict__ pin_w,
        const float* __restrict__ pout_w,
        short* __restrict__ Wc1, short* __restrict__ Wpj,
        short* __restrict__ Wpin, short* __restrict__ Wpout,
        float* __restrict__ bias1, float* __restrict__ Wkv0,
        float* __restrict__ bkv0, float* __restrict__ Wkv1,
        float* __restrict__ bkv1) {
    __shared__ float t[64][65];
    int bid = blockIdx.x;
    int tid = threadIdx.x;
    if (bid < 392) {
        int p0 = (bid % 49) * 64;
        int c0 = ((bid / 49) & 3) * 64;
        int b  = bid / 196;
        int pi = tid & 63, cj = tid >> 6;
        #pragma unroll
        for (int j = 0; j < 16; j++) {
            int c = cj * 16 + j;
            t[c][pi] = x[((size_t)(b * CDIM + c0 + c)) * NQ + p0 + pi];
        }
        __syncthreads();
        int ci = tid & 63, pj = tid >> 6;
        #pragma unroll
        for (int j = 0; j < 16; j++) {
            int p = pj * 16 + j;
            xT[((size_t)(b * NQ + p0 + p)) * CDIM + c0 + ci] = t[ci][p];
        }
        return;
    }
    int i = (bid - 392) * 256 + tid;
    if (i < 327680) {                       // Wc1 [1280][256]
        int r = i >> 8, k = i & 255, seg = r >> 8, n = r & 255;
        float v;
        if (seg == 0)      v = wq_w[n * 256 + k];
        else if (seg == 1) v = wq_w[65536 + n * 256 + k];
        else if (seg == 2) v = wq_w[131072 + n * 256 + k];
        else if (seg == 3) v = wk_w[131072 + n * 256 + k];
        else               v = wv_w[131072 + n * 256 + k];
        Wc1[i] = f2bf(v);
    } else if (i < 524288) {                // Wpj [256][768]
        int j = i - 327680;
        int n = j / 768, tt = j % 768, br = tt >> 8, k = tt & 255;
        Wpj[j] = f2bf(pj_w[br * 65536 + n * 256 + k]);
    } else if (i < 786432) {                // Wpin (row-permuted)
        int j = i - 524288;
        int r = j >> 8, k = j & 255;
        int o = (r & 3) * 256 + (r >> 2);
        Wpin[j] = f2bf(pin_w[o * 256 + k]);
    } else if (i < 917504) {                // Wpout
        int j = i - 786432;
        Wpout[j] = f2bf(pout_w[j]);
    } else if (i < 1048576) {               // Wkv0 fp32
        int j = i - 917504;
        int r = j >> 8, k = j & 255;
        Wkv0[j] = (r < 256) ? wk_w[r * 256 + k] : wv_w[(r - 256) * 256 + k];
    } else if (i < 1179648) {               // Wkv1 fp32
        int j = i - 1048576;
        int r = j >> 8, k = j & 255;
        Wkv1[j] = (r < 256) ? wk_w[65536 + r * 256 + k] : wv_w[65536 + (r - 256) * 256 + k];
    } else if (i < 1180928) {               // bias1
        int j = i - 1179648;
        float v;
        if (j < 768)       v = wq_b[j];
        else if (j < 1024) v = wk_b[512 + (j - 768)];
        else               v = wv_b[512 + (j - 1024)];
        bias1[j] = v;
    } else if (i < 1181440) {               // bkv0
        int j = i - 1180928;
        bkv0[j] = (j < 256) ? wk_b[j] : wv_b[j - 256];
    } else if (i < 1181952) {               // bkv1
        int j = i - 1181440;
        bkv1[j] = (j < 256) ? wk_b[256 + j] : wv_b[j];
    }
}

// ------------------------------------------------- 1b. pos conv + LN-gates (wave/token, no barriers)
__global__ __launch_bounds__(256) void k_posgates(
        const float* __restrict__ xT, const float* __restrict__ pw,
        const float* __restrict__ pb, const float* __restrict__ n1w,
        const float* __restrict__ n1b, const float* __restrict__ gw,
        const float* __restrict__ gb, float* __restrict__ feat,
        float* __restrict__ g, short* __restrict__ featb) {
    int wvid = threadIdx.x >> 6;
    int lane = threadIdx.x & 63;
    int c4 = lane * 4;
    float pwv[4][9];
    #pragma unroll
    for (int j = 0; j < 4; j++)
        #pragma unroll
        for (int i = 0; i < 9; i++) pwv[j][i] = pw[(c4 + j) * 9 + i];
    float4 pbv = *(const float4*)(pb + c4);
    float4 w1 = *(const float4*)(n1w + c4);
    float4 b1 = *(const float4*)(n1b + c4);
    float4 gw0 = *(const float4*)(gw + c4);
    float4 gw1 = *(const float4*)(gw + CDIM + c4);
    float4 gw2 = *(const float4*)(gw + 2 * CDIM + c4);
    float gb0 = gb[0], gb1 = gb[1], gb2 = gb[2];
    int tbase = blockIdx.x * 16 + wvid * 4;
    for (int t = 0; t < 4; t++) {
        int bn = tbase + t;
        int b = bn / NQ, n = bn % NQ;
        int y = n / WW, x = n % WW;
        const float* xb = xT + (size_t)b * NQ * CDIM;
        float4 a = *(const float4*)(xb + (size_t)n * CDIM + c4);
        float acc0 = a.x + pbv.x, acc1 = a.y + pbv.y;
        float acc2 = a.z + pbv.z, acc3 = a.w + pbv.w;
        #pragma unroll
        for (int dy = 0; dy < 3; dy++) {
            int yy = y + dy - 1;
            if (yy < 0 || yy >= HH) continue;
            #pragma unroll
            for (int dx = 0; dx < 3; dx++) {
                int xx = x + dx - 1;
                if (xx < 0 || xx >= WW) continue;
                float4 v = *(const float4*)(xb + ((size_t)(yy * WW + xx)) * CDIM + c4);
                int wi = dy * 3 + dx;
                acc0 += v.x * pwv[0][wi];
                acc1 += v.y * pwv[1][wi];
                acc2 += v.z * pwv[2][wi];
                acc3 += v.w * pwv[3][wi];
            }
        }
        *(float4*)(feat + (size_t)bn * CDIM + c4) = make_float4(acc0, acc1, acc2, acc3);
        short4 fb;
        fb.x = f2bf(acc0); fb.y = f2bf(acc1); fb.z = f2bf(acc2); fb.w = f2bf(acc3);
        *(short4*)(featb + (size_t)bn * CDIM + c4) = fb;
        float s = acc0 + acc1 + acc2 + acc3;
        #pragma unroll
        for (int off = 32; off > 0; off >>= 1) s += __shfl_xor(s, off);
        float mu = s * (1.f / CDIM);
        float d0 = acc0 - mu, d1 = acc1 - mu, d2 = acc2 - mu, d3 = acc3 - mu;
        float ss = d0 * d0 + d1 * d1 + d2 * d2 + d3 * d3;
        #pragma unroll
        for (int off = 32; off > 0; off >>= 1) ss += __shfl_xor(ss, off);
        float rstd = rsqrtf(ss * (1.f / CDIM) + 1e-6f);
        float q0 = d0 * rstd * w1.x + b1.x;
        float q1 = d1 * rstd * w1.y + b1.y;
        float q2 = d2 * rstd * w1.z + b1.z;
        float q3 = d3 * rstd * w1.w + b1.w;
        float p0 = q0 * gw0.x + q1 * gw0.y + q2 * gw0.z + q3 * gw0.w;
        float p1 = q0 * gw1.x + q1 * gw1.y + q2 * gw1.z + q3 * gw1.w;
        float p2 = q0 * gw2.x + q1 * gw2.y + q2 * gw2.z + q3 * gw2.w;
        #pragma unroll
        for (int off = 32; off > 0; off >>= 1) {
            p0 += __shfl_xor(p0, off);
            p1 += __shfl_xor(p1, off);
            p2 += __shfl_xor(p2, off);
        }
        if (lane == 0) {
            float l0 = p0 + gb0, l1 = p1 + gb1, l2 = p2 + gb2;
            float m3 = fmaxf(l0, fmaxf(l1, l2));
            float e0 = __expf(l0 - m3), e1 = __expf(l1 - m3), e2 = __expf(l2 - m3);
            float inv = 1.f / (e0 + e1 + e2);
            g[bn * 3 + 0] = e0 * inv;
            g[bn * 3 + 1] = e1 * inv;
            g[bn * 3 + 2] = e2 * inv;
        }
    }
}

// ------------------------------------------------- 2. block means + scores (fused)
__global__ __launch_bounds__(256) void k_blkscore(
        const float* __restrict__ feat, const float* __restrict__ s1w,
        const float* __restrict__ s1b, const float* __restrict__ s2w,
        const float* __restrict__ s2b, float* __restrict__ blk,
        float* __restrict__ scores) {
    __shared__ float sblk[256];
    __shared__ float red[128];
    int gid = blockIdx.x;
    int b = gid / NB, bid = gid % NB;
    int by = bid / 7, bx = bid % 7;
    int c = threadIdx.x;
    float s = 0.f;
    for (int iy = 0; iy < 8; iy++)
        for (int ix = 0; ix < 8; ix++) {
            int y = by * 8 + iy, xx = bx * 8 + ix;
            s += feat[((size_t)(b * NQ + y * WW + xx)) * CDIM + c];
        }
    s *= (1.f / 64.f);
    blk[(size_t)gid * CDIM + c] = s;
    sblk[c] = s;
    __syncthreads();
    if (c < 128) {
        const float* wrow = s1w + (size_t)c * CDIM;
        float acc = s1b[c];
        for (int k = 0; k < CDIM; k++) acc += sblk[k] * wrow[k];
        red[c] = gelu_exact(acc) * s2w[c];
    }
    __syncthreads();
    #pragma unroll
    for (int st = 64; st > 0; st >>= 1) {
        if (c < st) red[c] += red[c + st];
        __syncthreads();
    }
    if (c == 0) scores[gid] = red[0] + s2b[0];
}

// ------------------------------------------------- merged: QKV MFMA GEMM (blocks<980) + kv fp32 GEMM (blocks>=980)
// QKV: featb[NTOK,256] x Wc1 -> bufQh [NTOK,1280] f16 (64x128 tiles, BK=64)
// kv:  y<2: blk[98,256] x Wkv0 -> kvcmp; y==2: top-4 rows x Wkv1 -> kvsel
__global__ __launch_bounds__(256) void k_qkvkv(
        const short* __restrict__ A, const short* __restrict__ W,
        const float* __restrict__ bias, _Float16* __restrict__ C2,
        const float* __restrict__ blk, const float* __restrict__ Wkv0,
        const float* __restrict__ bkv0, _Float16* __restrict__ kvcmp,
        const float* __restrict__ scores, const float* __restrict__ Wkv1,
        const float* __restrict__ bkv1, _Float16* __restrict__ kvsel) {
    __shared__ __align__(16) char sm[27648];
    int bid = blockIdx.x;
    int tid = threadIdx.x;
    if (bid < 980) {
        const int K = 256, N = 1280;
        short (*As)[72] = (short(*)[72])sm;
        short (*Bs)[72] = (short(*)[72])(sm + 64 * 72 * 2);
        int wid = tid >> 6, lane = tid & 63;
        int wm = wid >> 1, wn = wid & 1;
        int m0 = (bid / 10) * 64, n0 = (bid % 10) * 128;
        f32x4 acc[2][4] = {};
        int ar = tid >> 2, ac = (tid & 3) * 16;
        int br = tid >> 1, bc = (tid & 1) * 32;
        int fr = lane & 15, fk = (lane >> 4) * 8;
        for (int k0 = 0; k0 < K; k0 += 64) {
            const short* ap = A + (size_t)(m0 + ar) * K + k0 + ac;
            bf16x8 a0 = *(const bf16x8*)(ap);
            bf16x8 a1 = *(const bf16x8*)(ap + 8);
            const short* wp = W + (size_t)(n0 + br) * K + k0 + bc;
            bf16x8 w0 = *(const bf16x8*)(wp);
            bf16x8 w1 = *(const bf16x8*)(wp + 8);
            bf16x8 w2 = *(const bf16x8*)(wp + 16);
            bf16x8 w3 = *(const bf16x8*)(wp + 24);
            __syncthreads();
            *(bf16x8*)&As[ar][ac] = a0;
            *(bf16x8*)&As[ar][ac + 8] = a1;
            *(bf16x8*)&Bs[br][bc] = w0;
            *(bf16x8*)&Bs[br][bc + 8] = w1;
            *(bf16x8*)&Bs[br][bc + 16] = w2;
            *(bf16x8*)&Bs[br][bc + 24] = w3;
            __syncthreads();
            #pragma unroll
            for (int kk = 0; kk < 64; kk += 32) {
                bf16x8 af[2], bf[4];
                #pragma unroll
                for (int mi = 0; mi < 2; mi++)
                    af[mi] = *(const bf16x8*)&As[wm * 32 + mi * 16 + fr][kk + fk];
                #pragma unroll
                for (int ni = 0; ni < 4; ni++)
                    bf[ni] = *(const bf16x8*)&Bs[wn * 64 + ni * 16 + fr][kk + fk];
                #pragma unroll
                for (int mi = 0; mi < 2; mi++)
                    #pragma unroll
                    for (int ni = 0; ni < 4; ni++)
                        acc[mi][ni] = __builtin_amdgcn_mfma_f32_16x16x32_bf16(
                            af[mi], bf[ni], acc[mi][ni], 0, 0, 0);
            }
        }
        int rsub = (lane >> 4) * 4;
        #pragma unroll
        for (int mi = 0; mi < 2; mi++) {
            #pragma unroll
            for (int ni = 0; ni < 4; ni++) {
                int col = n0 + wn * 64 + ni * 16 + (lane & 15);
                float bv = bias[col];
                #pragma unroll
                for (int r = 0; r < 4; r++) {
                    int row = m0 + wm * 32 + mi * 16 + rsub + r;
                    C2[(size_t)row * N + col] = (_Float16)(acc[mi][ni][r] + bv);
                }
            }
        }
    } else {
        float (*As)[68] = (float(*)[68])sm;
        float (*Ws)[68] = (float(*)[68])(sm + 16 * 68 * 4);
        float (*ssc)[NB] = (float(*)[NB])(sm + 2 * 16 * 68 * 4);
        int* sidx = (int*)(sm + 2 * 16 * 68 * 4 + 2 * NB * 4);
        int kid = bid - 980;
        int kvy = kid >> 3, kvx = kid & 7;
        const float* Wk; const float* biask; _Float16* C; int M;
        int m0;
        bool sel = (kvy == 2);
        if (!sel) { Wk = Wkv0; biask = bkv0; C = kvcmp; M = 98; m0 = kvy * 64; }
        else      { Wk = Wkv1; biask = bkv1; C = kvsel; M = 8;  m0 = 0; }
        const int N = 512, K = 256;
        const int tx = tid & 15, ty = tid >> 4;
        const int n0 = kvx * 64;
        const int lr = tid >> 2;
        const int lk = (tid & 3) * 4;
        if (sel) {
            if (tid < 2 * NB) ssc[tid / NB][tid % NB] = scores[tid];
            __syncthreads();
            if (tid < 2) {
                for (int t = 0; t < NTOPK; t++) {
                    int best = 0; float bv = -1e30f;
                    for (int m = 0; m < NB; m++)
                        if (ssc[tid][m] > bv) { bv = ssc[tid][m]; best = m; }
                    sidx[tid * 4 + t] = best; ssc[tid][best] = -1e30f;
                }
            }
            __syncthreads();
        }
        int gm = m0 + lr;
        int arow = gm;
        if (sel && gm < 8) arow = (gm >> 2) * NB + sidx[gm];
        float acc[4][4] = {};
        for (int k0 = 0; k0 < K; k0 += 16) {
            float4 av = make_float4(0.f, 0.f, 0.f, 0.f);
            if (gm < M) av = *(const float4*)(blk + (size_t)arow * K + k0 + lk);
            int gn = n0 + lr;
            float4 wv = *(const float4*)(Wk + (size_t)gn * K + k0 + lk);
            __syncthreads();
            As[lk][lr] = av.x; As[lk + 1][lr] = av.y; As[lk + 2][lr] = av.z; As[lk + 3][lr] = av.w;
            Ws[lk][lr] = wv.x; Ws[lk + 1][lr] = wv.y; Ws[lk + 2][lr] = wv.z; Ws[lk + 3][lr] = wv.w;
            __syncthreads();
            #pragma unroll
            for (int kk = 0; kk < 16; kk++) {
                const float4 a = *(const float4*)&As[kk][ty * 4];
                const float4 b = *(const float4*)&Ws[kk][tx * 4];
                acc[0][0] += a.x * b.x; acc[0][1] += a.x * b.y; acc[0][2] += a.x * b.z; acc[0][3] += a.x * b.w;
                acc[1][0] += a.y * b.x; acc[1][1] += a.y * b.y; acc[1][2] += a.y * b.z; acc[1][3] += a.y * b.w;
                acc[2][0] += a.z * b.x; acc[2][1] += a.z * b.y; acc[2][2] += a.z * b.z; acc[2][3] += a.z * b.w;
                acc[3][0] += a.w * b.x; acc[3][1] += a.w * b.y; acc[3][2] += a.w * b.z; acc[3][3] += a.w * b.w;
            }
        }
        #pragma unroll
        for (int i = 0; i < 4; i++) {
            int om = m0 + ty * 4 + i;
            if (om >= M) break;
            #pragma unroll
            for (int j = 0; j < 4; j++) {
                int gn = n0 + tx * 4 + j;
                C[(size_t)om * N + gn] = (_Float16)(acc[i][j] + biask[gn]);
            }
        }
    }
}

// ------------------------------------------------- MFMA GEMM 64x128, BK=64, bf16 A, f16 out
__global__ __launch_bounds__(256) void k_gemm64x128(
        const short* __restrict__ A, const short* __restrict__ W,
        const float* __restrict__ bias, int M, int N, int K,
        _Float16* __restrict__ C2) {
    __shared__ short As[64][72];
    __shared__ short Bs[128][72];
    int tid = threadIdx.x;
    int wid = tid >> 6, lane = tid & 63;
    int wm = wid >> 1, wn = wid & 1;
    int m0 = blockIdx.y * 64, n0 = blockIdx.x * 128;
    f32x4 acc[2][4] = {};
    int ar = tid >> 2, ac = (tid & 3) * 16;
    int br = tid >> 1, bc = (tid & 1) * 32;
    int fr = lane & 15, fk = (lane >> 4) * 8;
    for (int k0 = 0; k0 < K; k0 += 64) {
        const short* ap = A + (size_t)(m0 + ar) * K + k0 + ac;
        bf16x8 a0 = *(const bf16x8*)(ap);
        bf16x8 a1 = *(const bf16x8*)(ap + 8);
        const short* wp = W + (size_t)(n0 + br) * K + k0 + bc;
        bf16x8 w0 = *(const bf16x8*)(wp);
        bf16x8 w1 = *(const bf16x8*)(wp + 8);
        bf16x8 w2 = *(const bf16x8*)(wp + 16);
        bf16x8 w3 = *(const bf16x8*)(wp + 24);
        __syncthreads();
        *(bf16x8*)&As[ar][ac] = a0;
        *(bf16x8*)&As[ar][ac + 8] = a1;
        *(bf16x8*)&Bs[br][bc] = w0;
        *(bf16x8*)&Bs[br][bc + 8] = w1;
        *(bf16x8*)&Bs[br][bc + 16] = w2;
        *(bf16x8*)&Bs[br][bc + 24] = w3;
        __syncthreads();
        #pragma unroll
        for (int kk = 0; kk < 64; kk += 32) {
            bf16x8 af[2], bf[4];
            #pragma unroll
            for (int mi = 0; mi < 2; mi++)
                af[mi] = *(const bf16x8*)&As[wm * 32 + mi * 16 + fr][kk + fk];
            #pragma unroll
            for (int ni = 0; ni < 4; ni++)
                bf[ni] = *(const bf16x8*)&Bs[wn * 64 + ni * 16 + fr][kk + fk];
            #pragma unroll
            for (int mi = 0; mi < 2; mi++)
                #pragma unroll
                for (int ni = 0; ni < 4; ni++)
                    acc[mi][ni] = __builtin_amdgcn_mfma_f32_16x16x32_bf16(
                        af[mi], bf[ni], acc[mi][ni], 0, 0, 0);
        }
    }
    int rsub = (lane >> 4) * 4;
    #pragma unroll
    for (int mi = 0; mi < 2; mi++) {
        #pragma unroll
        for (int ni = 0; ni < 4; ni++) {
            int col = n0 + wn * 64 + ni * 16 + (lane & 15);
            float bv = bias ? bias[col] : 0.f;
            #pragma unroll
            for (int r = 0; r < 4; r++) {
                int row = m0 + wm * 32 + mi * 16 + rsub + r;
                C2[(size_t)row * N + col] = (_Float16)(acc[mi][ni][r] + bv);
            }
        }
    }
}

// ------------------------------------------------- MFMA GEMM 64x64, BK=64, bf16 A (resid epi)
__global__ __launch_bounds__(256) void k_gemm64(
        const short* __restrict__ A, const short* __restrict__ W,
        const float* __restrict__ bias, float* __restrict__ C,
        int M, int N, int K,
        const float* __restrict__ resid, const float* __restrict__ g3,
        const float* __restrict__ pjb, short* __restrict__ Cb) {
    __shared__ short As[64][72];
    __shared__ short Bs[64][72];
    int tid = threadIdx.x;
    int wid = tid >> 6, lane = tid & 63;
    int wm = wid >> 1, wn = wid & 1;
    int m0 = blockIdx.y * 64, n0 = blockIdx.x * 64;
    f32x4 acc[2][2] = {};
    int ar = tid >> 2, ac = (tid & 3) * 16;
    int fr = lane & 15, fk = (lane >> 4) * 8;
    for (int k0 = 0; k0 < K; k0 += 64) {
        const short* ap = A + (size_t)(m0 + ar) * K + k0 + ac;
        bf16x8 a0 = *(const bf16x8*)(ap);
        bf16x8 a1 = *(const bf16x8*)(ap + 8);
        const short* wp = W + (size_t)(n0 + ar) * K + k0 + ac;
        bf16x8 w0 = *(const bf16x8*)(wp);
        bf16x8 w1 = *(const bf16x8*)(wp + 8);
        __syncthreads();
        *(bf16x8*)&As[ar][ac] = a0;
        *(bf16x8*)&As[ar][ac + 8] = a1;
        *(bf16x8*)&Bs[ar][ac] = w0;
        *(bf16x8*)&Bs[ar][ac + 8] = w1;
        __syncthreads();
        #pragma unroll
        for (int kk = 0; kk < 64; kk += 32) {
            bf16x8 af[2], bf[2];
            #pragma unroll
            for (int mi = 0; mi < 2; mi++)
                af[mi] = *(const bf16x8*)&As[wm * 32 + mi * 16 + fr][kk + fk];
            #pragma unroll
            for (int ni = 0; ni < 2; ni++)
                bf[ni] = *(const bf16x8*)&Bs[wn * 32 + ni * 16 + fr][kk + fk];
            #pragma unroll
            for (int mi = 0; mi < 2; mi++)
                #pragma unroll
                for (int ni = 0; ni < 2; ni++)
                    acc[mi][ni] = __builtin_amdgcn_mfma_f32_16x16x32_bf16(
                        af[mi], bf[ni], acc[mi][ni], 0, 0, 0);
        }
    }
    int rsub = (lane >> 4) * 4;
    #pragma unroll
    for (int mi = 0; mi < 2; mi++) {
        #pragma unroll
        for (int ni = 0; ni < 2; ni++) {
            int col = n0 + wn * 32 + ni * 16 + (lane & 15);
            #pragma unroll
            for (int r = 0; r < 4; r++) {
                int row = m0 + wm * 32 + mi * 16 + rsub + r;
                float v = acc[mi][ni][r];
                if (resid) {
                    v += resid[(size_t)row * N + col]
                       + g3[row * 3 + 0] * pjb[col]
                       + g3[row * 3 + 1] * pjb[256 + col]
                       + g3[row * 3 + 2] * pjb[512 + col];
                } else if (bias) {
                    v += bias[col];
                }
                C[(size_t)row * N + col] = v;
                if (Cb) Cb[(size_t)row * N + col] = f2bf(v);
            }
        }
    }
}

// ------------------------------------------------- pout GEMM + final LN + NCHW write (fused)
__global__ __launch_bounds__(256) void k_poutln(
        const short* __restrict__ G, const short* __restrict__ W,
        const float* __restrict__ ym, const float* __restrict__ n2w,
        const float* __restrict__ n2b, float* __restrict__ out) {
    __shared__ short As[32][72];
    __shared__ float redS[4][36];
    __shared__ float redQ[4][36];
    int tid = threadIdx.x;
    int wid = tid >> 6, lane = tid & 63;
    int bx = blockIdx.x;
    int b = bx / 98;
    int t0g = bx * 32;                 // global token base
    int p0 = (bx % 98) * 32;           // pixel base within batch
    f32x4 acc[2][4] = {};
    int ar = tid >> 3, ac = (tid & 7) * 8;
    int fr = lane & 15, fk = (lane >> 4) * 8;
    const short* Wb = W + (size_t)(wid * 64) * 512;
    for (int k0 = 0; k0 < 512; k0 += 64) {
        bf16x8 a0 = *(const bf16x8*)(G + (size_t)(t0g + ar) * 512 + k0 + ac);
        __syncthreads();
        *(bf16x8*)&As[ar][ac] = a0;
        __syncthreads();
        #pragma unroll
        for (int kk = 0; kk < 64; kk += 32) {
            bf16x8 af[2], bf[4];
            #pragma unroll
            for (int mi = 0; mi < 2; mi++)
                af[mi] = *(const bf16x8*)&As[mi * 16 + fr][kk + fk];
            #pragma unroll
            for (int ni = 0; ni < 4; ni++)
                bf[ni] = *(const bf16x8*)(Wb + (size_t)(ni * 16 + fr) * 512 + k0 + kk + fk);
            #pragma unroll
            for (int mi = 0; mi < 2; mi++)
                #pragma unroll
                for (int ni = 0; ni < 4; ni++)
                    acc[mi][ni] = __builtin_amdgcn_mfma_f32_16x16x32_bf16(
                        af[mi], bf[ni], acc[mi][ni], 0, 0, 0);
        }
    }
    int rsub = (lane >> 4) * 4;
    float v[2][4][4];
    #pragma unroll
    for (int mi = 0; mi < 2; mi++)
        #pragma unroll
        for (int ni = 0; ni < 4; ni++) {
            int col = wid * 64 + ni * 16 + fr;
            #pragma unroll
            for (int r = 0; r < 4; r++) {
                int row = mi * 16 + rsub + r;
                v[mi][ni][r] = acc[mi][ni][r] + ym[(size_t)(t0g + row) * CDIM + col];
            }
        }
    #pragma unroll
    for (int mi = 0; mi < 2; mi++) {
        #pragma unroll
        for (int r = 0; r < 4; r++) {
            float s = v[mi][0][r] + v[mi][1][r] + v[mi][2][r] + v[mi][3][r];
            s += __shfl_xor(s, 1); s += __shfl_xor(s, 2);
            s += __shfl_xor(s, 4); s += __shfl_xor(s, 8);
            if (fr == 0) redS[wid][mi * 16 + rsub + r] = s;
        }
    }
    __syncthreads();
    float mu[2][4];
    #pragma unroll
    for (int mi = 0; mi < 2; mi++)
        #pragma unroll
        for (int r = 0; r < 4; r++) {
            int row = mi * 16 + rsub + r;
            mu[mi][r] = (redS[0][row] + redS[1][row] + redS[2][row] + redS[3][row])
                        * (1.f / CDIM);
        }
    #pragma unroll
    for (int mi = 0; mi < 2; mi++) {
        #pragma unroll
        for (int r = 0; r < 4; r++) {
            float m = mu[mi][r];
            float d0 = v[mi][0][r] - m, d1 = v[mi][1][r] - m;
            float d2 = v[mi][2][r] - m, d3 = v[mi][3][r] - m;
            float q = d0 * d0 + d1 * d1 + d2 * d2 + d3 * d3;
            q += __shfl_xor(q, 1); q += __shfl_xor(q, 2);
            q += __shfl_xor(q, 4); q += __shfl_xor(q, 8);
            if (fr == 0) redQ[wid][mi * 16 + rsub + r] = q;
        }
    }
    __syncthreads();
    float rstd[2][4];
    #pragma unroll
    for (int mi = 0; mi < 2; mi++)
        #pragma unroll
        for (int r = 0; r < 4; r++) {
            int row = mi * 16 + rsub + r;
            float var = (redQ[0][row] + redQ[1][row] + redQ[2][row] + redQ[3][row])
                        * (1.f / CDIM);
            rstd[mi][r] = rsqrtf(var + 1e-6f);
        }
    #pragma unroll
    for (int mi = 0; mi < 2; mi++) {
        #pragma unroll
        for (int ni = 0; ni < 4; ni++) {
            int col = wid * 64 + ni * 16 + fr;
            float wgt = n2w[col], bia = n2b[col];
            float4 o;
            o.x = (v[mi][ni][0] - mu[mi][0]) * rstd[mi][0] * wgt + bia;
            o.y = (v[mi][ni][1] - mu[mi][1]) * rstd[mi][1] * wgt + bia;
            o.z = (v[mi][ni][2] - mu[mi][2]) * rstd[mi][2] * wgt + bia;
            o.w = (v[mi][ni][3] - mu[mi][3]) * rstd[mi][3] * wgt + bia;
            *(float4*)(out + ((size_t)(b * CDIM + col)) * NQ + p0 + mi * 16 + rsub) = o;
        }
    }
}

// ------------------------------------------------- fused attention, f16 LDS-staged K/V
// 512 threads, 16 tokens/block.  blocks [0,392): cmp+sel (16 linear tokens);
// [392,784): window (4x4 token tile, 10x10 px union).
__global__ __launch_bounds__(512) void k_attn_lds(
        const _Float16* __restrict__ bufQ, const _Float16* __restrict__ kvc,
        const _Float16* __restrict__ kvs, short* __restrict__ Acatb,
        const float* __restrict__ g) {
    __shared__ uint4 buf[100 * 32];       // 51.2 KB
    int tid = threadIdx.x;
    int wid = tid >> 6;                   // 0..7
    int lane = tid & 63;
    int l = tid & 31;                     // lane within token group
    int tk = tid >> 5;                    // token 0..15 within block
    int dg = l & 3;
    int co = l * 8;                       // channel offset
    const float scale = 0.17677669529663687f;

    if (blockIdx.x < 392) {
        // ======================= cmp + sel =======================
        int bid = blockIdx.x;
        int swz = (bid & 7) * 49 + (bid >> 3);    // bijective XCD swizzle (392=8*49)
        int t0 = swz * 16;
        int tok = t0 + tk;
        int b = t0 / NQ;
        const _Float16* kb = kvc + (size_t)b * NB * 512;
        for (int p = wid * 2; p < NB + 1; p += 16) {
            int myp = p + (lane >> 5);
            if (myp > NB - 1) myp = NB - 1;
            gld16((const uint4*)(kb + (size_t)myp * 512) + (lane & 31), &buf[p * 32]);
        }
        const _Float16* qrow = bufQ + (size_t)tok * QSTRH;
        float gate0 = g[tok * 3 + 0];
        float gate1 = g[tok * 3 + 1];
        short* orow = Acatb + (size_t)tok * ASTR;
        h2x4 qv = *(const h2x4*)(qrow + co);
        __syncthreads();                  // K staged
        float sc[13];
        sc[12] = -1e30f;
        #pragma unroll
        for (int m = 0; m < NB; m++) {
            h2x4 kv = *(const h2x4*)&buf[m * 32 + l];
            float acc = fdot2h(qv.x, kv.x, 0.f);
            acc = fdot2h(qv.y, kv.y, acc);
            acc = fdot2h(qv.z, kv.z, acc);
            acc = fdot2h(qv.w, kv.w, acc);
            acc += __shfl_xor(acc, 1);
            acc += __shfl_xor(acc, 2);
            if ((m & 3) == dg) sc[m >> 2] = acc * scale;
        }
        float mx = sc[0];
        #pragma unroll
        for (int i = 1; i < 13; i++) mx = fmaxf(mx, sc[i]);
        mx = fmaxf(mx, __shfl_xor(mx, 1));
        mx = fmaxf(mx, __shfl_xor(mx, 2));
        float sum = 0.f;
        #pragma unroll
        for (int i = 0; i < 13; i++) { sc[i] = __expf(sc[i] - mx); sum += sc[i]; }
        sum += __shfl_xor(sum, 1);
        sum += __shfl_xor(sum, 2);
        float inv_c = 1.f / sum;
        __syncthreads();                  // all waves done reading K
        for (int p = wid * 2; p < NB + 1; p += 16) {
            int myp = p + (lane >> 5);
            if (myp > NB - 1) myp = NB - 1;
            gld16((const uint4*)(kb + (size_t)myp * 512 + 256) + (lane & 31), &buf[p * 32]);
        }
        {
            const _Float16* ksb = kvs + (size_t)b * NTOPK * 512;
            h2x4 qs = *(const h2x4*)(qrow + 256 + co);
            float sv = 0.f;
            #pragma unroll
            for (int m = 0; m < NTOPK; m++) {
                h2x4 kk = *(const h2x4*)(ksb + (size_t)m * 512 + co);
                float acc = fdot2h(qs.x, kk.x, 0.f);
                acc = fdot2h(qs.y, kk.y, acc);
                acc = fdot2h(qs.z, kk.z, acc);
                acc = fdot2h(qs.w, kk.w, acc);
                acc += __shfl_xor(acc, 1);
                acc += __shfl_xor(acc, 2);
                if (m == dg) sv = acc * scale;
            }
            float mxs = sv;
            mxs = fmaxf(mxs, __shfl_xor(mxs, 1));
            mxs = fmaxf(mxs, __shfl_xor(mxs, 2));
            float e = __expf(sv - mxs);
            float sums = e;
            sums += __shfl_xor(sums, 1);
            sums += __shfl_xor(sums, 2);
            float invs = 1.f / sums;
            float o[8];
            #pragma unroll
            for (int d = 0; d < 8; d++) o[d] = 0.f;
            #pragma unroll
            for (int m = 0; m < NTOPK; m++) {
                float pw = __shfl(e, m, 4);
                h2x4 vv = *(const h2x4*)(ksb + (size_t)m * 512 + 256 + co);
                o[0] += pw * (float)vv.x[0]; o[1] += pw * (float)vv.x[1];
                o[2] += pw * (float)vv.y[0]; o[3] += pw * (float)vv.y[1];
                o[4] += pw * (float)vv.z[0]; o[5] += pw * (float)vv.z[1];
                o[6] += pw * (float)vv.w[0]; o[7] += pw * (float)vv.w[1];
            }
            float gg = gate1 * invs;
            bf16x8 ov;
            #pragma unroll
            for (int d = 0; d < 8; d++) ov[d] = f2bf(o[d] * gg);
            *(bf16x8*)(orow + 256 + co) = ov;
        }
        __syncthreads();                  // V staged
        {
            float o[8];
            #pragma unroll
            for (int d = 0; d < 8; d++) o[d] = 0.f;
            #pragma unroll
            for (int m = 0; m < NB; m++) {
                float pw = __shfl(sc[m >> 2], m & 3, 4);
                h2x4 vv = *(const h2x4*)&buf[m * 32 + l];
                o[0] += pw * (float)vv.x[0]; o[1] += pw * (float)vv.x[1];
                o[2] += pw * (float)vv.y[0]; o[3] += pw * (float)vv.y[1];
                o[4] += pw * (float)vv.z[0]; o[5] += pw * (float)vv.z[1];
                o[6] += pw * (float)vv.w[0]; o[7] += pw * (float)vv.w[1];
            }
            float gg = gate0 * inv_c;
            bf16x8 ov;
            #pragma unroll
            for (int d = 0; d < 8; d++) ov[d] = f2bf(o[d] * gg);
            *(bf16x8*)(orow + co) = ov;
        }
    } else {
        // ======================= window (4x4 tile) =======================
        int bid = blockIdx.x - 392;
        int swz = (bid & 7) * 49 + (bid >> 3);
        int b = swz / 196;
        int r = swz % 196;
        int y0 = (r / 14) * 4;
        int x0 = (r % 14) * 4;
        int ty = tk >> 2, tx = tk & 3;
        int y = y0 + ty, x = x0 + tx;
        int tok = b * NQ + y * WW + x;
        const _Float16* KVb = bufQ + (size_t)b * NQ * QSTRH;
        for (int p = wid * 2; p < 100; p += 16) {
            int pp = p + (lane >> 5);
            int pr = pp / 10, pc = pp - pr * 10;
            int gy = min(max(y0 + pr - 3, 0), HH - 1);
            int gx = min(max(x0 + pc - 3, 0), WW - 1);
            gld16((const uint4*)(KVb + (size_t)(gy * WW + gx) * QSTRH + 768) + (lane & 31),
                  &buf[p * 32]);
        }
        h2x4 qv = *(const h2x4*)(bufQ + (size_t)tok * QSTRH + 512 + co);
        float gate = g[tok * 3 + 2];
        __syncthreads();                  // K staged
        float sw[13];
        sw[12] = -1e30f;
        #pragma unroll
        for (int dy = 0; dy < 7; dy++) {
            #pragma unroll
            for (int dx = 0; dx < 7; dx++) {
                int p = (ty + dy) * 10 + tx + dx;
                h2x4 kv = *(const h2x4*)&buf[p * 32 + l];
                float acc = fdot2h(qv.x, kv.x, 0.f);
                acc = fdot2h(qv.y, kv.y, acc);
                acc = fdot2h(qv.z, kv.z, acc);
                acc = fdot2h(qv.w, kv.w, acc);
                acc += __shfl_xor(acc, 1);
                acc += __shfl_xor(acc, 2);
                int m = dy * 7 + dx;
                if ((m & 3) == dg) sw[m >> 2] = acc * scale;
            }
        }
        float mx = sw[0];
        #pragma unroll
        for (int i = 1; i < 13; i++) mx = fmaxf(mx, sw[i]);
        mx = fmaxf(mx, __shfl_xor(mx, 1));
        mx = fmaxf(mx, __shfl_xor(mx, 2));
        float sum = 0.f;
        #pragma unroll
        for (int i = 0; i < 13; i++) { sw[i] = __expf(sw[i] - mx); sum += sw[i]; }
        sum += __shfl_xor(sum, 1);
        sum += __shfl_xor(sum, 2);
        float inv = 1.f / sum;
        __syncthreads();                  // all waves done reading K
        for (int p = wid * 2; p < 100; p += 16) {
            int pp = p + (lane >> 5);
            int pr = pp / 10, pc = pp - pr * 10;
            int gy = min(max(y0 + pr - 3, 0), HH - 1);
            int gx = min(max(x0 + pc - 3, 0), WW - 1);
            gld16((const uint4*)(KVb + (size_t)(gy * WW + gx) * QSTRH + 1024) + (lane & 31),
                  &buf[p * 32]);
        }
        __syncthreads();                  // V staged
        float o[8];
        #pragma unroll
        for (int d = 0; d < 8; d++) o[d] = 0.f;
        #pragma unroll
        for (int dy = 0; dy < 7; dy++) {
            #pragma unroll
            for (int dx = 0; dx < 7; dx++) {
                int p = (ty + dy) * 10 + tx + dx;
                int m = dy * 7 + dx;
                float pw = __shfl(sw[m >> 2], m & 3, 4);
                h2x4 vv = *(const h2x4*)&buf[p * 32 + l];
                o[0] += pw * (float)vv.x[0]; o[1] += pw * (float)vv.x[1];
                o[2] += pw * (float)vv.y[0]; o[3] += pw * (float)vv.y[1];
                o[4] += pw * (float)vv.z[0]; o[5] += pw * (float)vv.z[1];
                o[6] += pw * (float)vv.w[0]; o[7] += pw * (float)vv.w[1];
            }
        }
        float gg = gate * inv;
        short* op = Acatb + (size_t)tok * ASTR + 512 + co;
        bf16x8 ov;
        #pragma unroll
        for (int d = 0; d < 8; d++) ov[d] = f2bf(o[d] * gg);
        *(bf16x8*)(op) = ov;
    }
}

// ------------------------------------------------- dwconv 3x3 + GLU (2 y-rows/block, h4 loads)
// 4-row halo serves both output rows: per-output loads drop 3 -> 2.
__global__ __launch_bounds__(256) void k_dwglu2(
        const _Float16* __restrict__ t, const float* __restrict__ w,
        short* __restrict__ G) {
    int gid = blockIdx.x;
    int xq = gid & 7;                 // 8 chunks of 7 pixels
    int y0 = ((gid >> 3) % (HH / 2)) * 2;
    int b = gid / ((HH / 2) * 8);
    int c = threadIdx.x;
    float wv[9][4];
    #pragma unroll
    for (int i = 0; i < 9; i++)
        #pragma unroll
        for (int j = 0; j < 4; j++) wv[i][j] = w[i * HID2 + j * 256 + c];
    const _Float16* tb = t + (size_t)b * NQ * HID2;
    short* Gbase = G + (size_t)b * NQ * HIDM;
    int x0 = xq * 7;
    float col[3][4][4];               // [xslot][row y0-1..y0+2][j]
    #pragma unroll
    for (int ci = 0; ci < 2; ci++) {
        int xx = x0 - 1 + ci;
        #pragma unroll
        for (int r = 0; r < 4; r++) {
            int yy = y0 + r - 1;
            bool ok = (xx >= 0) && (yy >= 0) && (yy < HH);
            h4 v = {};
            if (ok) v = *(const h4*)(tb + ((size_t)(yy * WW + xx)) * HID2 + c * 4);
            #pragma unroll
            for (int j = 0; j < 4; j++) col[ci][r][j] = (float)v[j];
        }
    }
    #pragma unroll
    for (int i = 0; i < 7; i++) {
        int xx = x0 + i;
        {
            int xl = xx + 1;
            #pragma unroll
            for (int r = 0; r < 4; r++) {
                int yy = y0 + r - 1;
                bool ok = (xl < WW) && (yy >= 0) && (yy < HH);
                h4 v = {};
                if (ok) v = *(const h4*)(tb + ((size_t)(yy * WW + xl)) * HID2 + c * 4);
                #pragma unroll
                for (int j = 0; j < 4; j++) col[(i + 2) % 3][r][j] = (float)v[j];
            }
        }
        #pragma unroll
        for (int o = 0; o < 2; o++) {
            float a0 = 0.f, a1 = 0.f, a2 = 0.f, a3 = 0.f;
            #pragma unroll
            for (int r = 0; r < 3; r++) {
                #pragma unroll
                for (int dxx = 0; dxx < 3; dxx++) {
                    const float* cc = col[(i + dxx) % 3][r + o];
                    int wi = r * 3 + dxx;
                    a0 += cc[0] * wv[wi][0];
                    a1 += cc[1] * wv[wi][1];
                    a2 += cc[2] * wv[wi][2];
                    a3 += cc[3] * wv[wi][3];
                }
            }
            short* Gb = Gbase + (size_t)((y0 + o) * WW + xx) * HIDM;
            Gb[c]       = f2bf(gelu_exact(a0) * a2);
            Gb[c + 256] = f2bf(gelu_exact(a1) * a3);
        }
    }
}

// ================================================================ host
extern "C" void kernel_launch(void* const* d_in, const int* in_sizes, int n_in,
                              void* d_out, int out_size, void* d_ws, size_t ws_size,
                              hipStream_t stream) {
    const float* x     = (const float*)d_in[0];
    const float* pos_w = (const float*)d_in[1];
    const float* pos_b = (const float*)d_in[2];
    const float* n1w   = (const float*)d_in[3];
    const float* n1b   = (const float*)d_in[4];
    const float* n2w   = (const float*)d_in[5];
    const float* n2b   = (const float*)d_in[6];
    const float* wq_w  = (const float*)d_in[7];
    const float* wq_b  = (const float*)d_in[8];
    const float* wk_w  = (const float*)d_in[9];
    const float* wk_b  = (const float*)d_in[10];
    const float* wv_w  = (const float*)d_in[11];
    const float* wv_b  = (const float*)d_in[12];
    const float* pj_w  = (const float*)d_in[13];
    const float* pj_b  = (const float*)d_in[14];
    const float* s1w   = (const float*)d_in[15];
    const float* s1b   = (const float*)d_in[16];
    const float* s2w   = (const float*)d_in[17];
    const float* s2b   = (const float*)d_in[18];
    const float* gw    = (const float*)d_in[19];
    const float* gb    = (const float*)d_in[20];
    const float* pinw  = (const float*)d_in[21];
    const float* dww   = (const float*)d_in[22];
    const float* poutw = (const float*)d_in[23];
    float* out = (float*)d_out;
    float* ws  = (float*)d_ws;

    const size_t SZ = (size_t)NTOK * CDIM;
    float* feat = ws;                               // [NTOK,256] fp32
    _Float16* bufQh = (_Float16*)(feat + SZ);       // [NTOK,1280] f16 (q0|q1|q2|kw|vw)
    float* R1   = (float*)(bufQh + (size_t)NTOK * QSTRH);  // xT / Acatb / T1h share
    float* xT   = R1;                               // [NTOK,256] fp32
    short* Acatb = (short*)R1;                      // [NTOK,768] bf16
    _Float16* T1h = (_Float16*)R1;                  // [NTOK,1024] f16 (permuted channels)
    float* ym   = R1 + (size_t)NTOK * 512;          // [NTOK,256] fp32
    short* featb = (short*)(ym + SZ);               // [NTOK,256] bf16
    short* ymb   = featb + (size_t)NTOK * CDIM;     // [NTOK,256] bf16
    float* blk   = (float*)(ymb + (size_t)NTOK * CDIM);  // [98,256] fp32
    _Float16* kvcmp = (_Float16*)(blk + 98 * 256);  // [98,512] f16
    _Float16* kvsel = kvcmp + 98 * 512;             // [8,512] f16
    float* scores = (float*)(kvsel + 8 * 512);      // [128]
    float* g      = scores + 128;                   // [NTOK,3]
    float* bias1  = g + (size_t)NTOK * 3;           // [1280]
    float* Wkv0   = bias1 + 1280;                   // [512,256] fp32
    float* bkv0   = Wkv0 + 512 * 256;
    float* Wkv1   = bkv0 + 512;
    float* bkv1   = Wkv1 + 512 * 256;
    short* Wc1    = (short*)(bkv1 + 512);           // bf16 [1280,256]
    short* Wpj    = Wc1 + 1280 * 256;               // bf16 [256,768]
    short* Wpin   = Wpj + 256 * 768;                // bf16 [1024,256] (row-permuted)
    short* Wpout  = Wpin + 1024 * 256;              // bf16 [256,512]
    short* G      = (short*)bufQh;                  // alias [NTOK,512] bf16 (bufQh dead after attn)

    // merged transpose + weight convert (independent work, one launch)
    hipLaunchKernelGGL(k_init, dim3(392 + 4618), dim3(256), 0, stream,
                       x, xT, wq_w, wk_w, wv_w, wq_b, wk_b, wv_b, pj_w, pinw, poutw,
                       Wc1, Wpj, Wpin, Wpout, bias1, Wkv0, bkv0, Wkv1, bkv1);
    hipLaunchKernelGGL(k_posgates, dim3(NTOK / 16), dim3(256), 0, stream,
                       xT, pos_w, pos_b, n1w, n1b, gw, gb, feat, g, featb);
    hipLaunchKernelGGL(k_blkscore, dim3(BATCH * NB), dim3(256), 0, stream,
                       feat, s1w, s1b, s2w, s2b, blk, scores);
    // merged QKV projection (980 blocks) + kvcmp/kvsel fp32 GEMM (24 blocks)
    hipLaunchKernelGGL(k_qkvkv, dim3(1004), dim3(256), 0, stream,
                       featb, Wc1, bias1, bufQh,
                       blk, Wkv0, bkv0, kvcmp, scores, Wkv1, bkv1, kvsel);
    // all attention branches (16 tokens/block, f16 LDS-staged K/V) -> gated Acatb (bf16)
    hipLaunchKernelGGL(k_attn_lds, dim3(784), dim3(512), 0, stream,
                       bufQh, kvcmp, kvsel, Acatb, g);
    // fused output projection + residual + gated biases -> ym fp32 + ymb bf16  (392 blocks)
    hipLaunchKernelGGL(k_gemm64, dim3(CDIM / 64, NTOK / 64), dim3(256), 0, stream,
                       Acatb, Wpj, nullptr, ym, NTOK, CDIM, ASTR, feat, g, pj_b, ymb);
    // DBFFN: pin (row-permuted W) -> T1h f16 (channel-interleaved)  (784 blocks)
    hipLaunchKernelGGL(k_gemm64x128, dim3(HID2 / 128, NTOK / 64), dim3(256), 0, stream,
                       ymb, Wpin, nullptr, NTOK, HID2, 256, T1h);
    hipLaunchKernelGGL(k_dwglu2, dim3(BATCH * (HH / 2) * 8), dim3(256), 0, stream, T1h, dww, G);
    // fused pout GEMM + final LN + NCHW write
    hipLaunchKernelGGL(k_poutln, dim3(NTOK / 32), dim3(256), 0, stream,
                       G, Wpout, ym, n2w, n2b, out);
}

// Round 12
// 157.254 us; speedup vs baseline: 1.0113x; 1.0009x over previous
//
#include <hip/hip_runtime.h>

#define BATCH 2
#define CDIM 256
#define HEADS 8
#define HD 32
#define HH 56
#define WW 56
#define NQ 3136          // 56*56
#define NTOK 6272        // BATCH*NQ
#define NB 49
#define NTOPK 4
#define HID2 1024        // 2*HID
#define HIDM 512         // HID
#define QSTRH 1280       // bufQh row stride (f16): [q0|q1|q2|kw|vw]
#define ASTR 768         // Acatb row stride (bf16)

typedef short bf16x8 __attribute__((ext_vector_type(8)));
typedef float f32x4 __attribute__((ext_vector_type(4)));
typedef _Float16 h2 __attribute__((ext_vector_type(2)));
typedef _Float16 h4 __attribute__((ext_vector_type(4)));
struct __align__(16) h2x4 { h2 x, y, z, w; };

// ---------------------------------------------------------------- utilities
__device__ __forceinline__ float gelu_exact(float x) {
    return 0.5f * x * (1.f + erff(x * 0.70710678118654752f));
}

__device__ __forceinline__ short f2bf(float f) {
    union { float f; unsigned u; } v; v.f = f;
    unsigned r = v.u + 0x7FFFu + ((v.u >> 16) & 1u);
    return (short)(r >> 16);
}

__device__ __forceinline__ float fdot2h(h2 a, h2 b, float c) {
#if __has_builtin(__builtin_amdgcn_fdot2)
    return __builtin_amdgcn_fdot2(a, b, c, false);
#else
    return c + (float)a[0] * (float)b[0] + (float)a[1] * (float)b[1];
#endif
}

// async global->LDS, 16B per lane; LDS dest is wave-uniform base + lane*16
__device__ __forceinline__ void gld16(const void* gsrc, void* ldst) {
    __builtin_amdgcn_global_load_lds(
        (const __attribute__((address_space(1))) void*)gsrc,
        (__attribute__((address_space(3))) void*)ldst, 16, 0, 0);
}

// ------------------------------------------------- 0. init: NCHW->NHWC transpose + weight convert (merged)
// blocks [0,392): transpose x -> xT; blocks [392,5010): weight convert.
// Wpin rows are PERMUTED: new row p holds original out-channel
// (p&3)*256 + (p>>2) (enables 8B h4 loads in k_dwglu2).
__global__ __launch_bounds__(256) void k_init(
        const float* __restrict__ x, float* __restrict__ xT,
        const float* __restrict__ wq_w, const float* __restrict__ wk_w,
        const float* __restrict__ wv_w, const float* __restrict__ wq_b,
        const float* __restrict__ wk_b, const float* __restrict__ wv_b,
        const float* __restrict__ pj_w, const float* __restrict__ pin_w,
        const float* __restrict__ pout_w,
        short* __restrict__ Wc1, short* __restrict__ Wpj,
        short* __restrict__ Wpin, short* __restrict__ Wpout,
        float* __restrict__ bias1, float* __restrict__ Wkv0,
        float* __restrict__ bkv0, float* __restrict__ Wkv1,
        float* __restrict__ bkv1) {
    __shared__ float t[64][65];
    int bid = blockIdx.x;
    int tid = threadIdx.x;
    if (bid < 392) {
        int p0 = (bid % 49) * 64;
        int c0 = ((bid / 49) & 3) * 64;
        int b  = bid / 196;
        int pi = tid & 63, cj = tid >> 6;
        #pragma unroll
        for (int j = 0; j < 16; j++) {
            int c = cj * 16 + j;
            t[c][pi] = x[((size_t)(b * CDIM + c0 + c)) * NQ + p0 + pi];
        }
        __syncthreads();
        int ci = tid & 63, pj = tid >> 6;
        #pragma unroll
        for (int j = 0; j < 16; j++) {
            int p = pj * 16 + j;
            xT[((size_t)(b * NQ + p0 + p)) * CDIM + c0 + ci] = t[ci][p];
        }
        return;
    }
    int i = (bid - 392) * 256 + tid;
    if (i < 327680) {                       // Wc1 [1280][256]
        int r = i >> 8, k = i & 255, seg = r >> 8, n = r & 255;
        float v;
        if (seg == 0)      v = wq_w[n * 256 + k];
        else if (seg == 1) v = wq_w[65536 + n * 256 + k];
        else if (seg == 2) v = wq_w[131072 + n * 256 + k];
        else if (seg == 3) v = wk_w[131072 + n * 256 + k];
        else               v = wv_w[131072 + n * 256 + k];
        Wc1[i] = f2bf(v);
    } else if (i < 524288) {                // Wpj [256][768]
        int j = i - 327680;
        int n = j / 768, tt = j % 768, br = tt >> 8, k = tt & 255;
        Wpj[j] = f2bf(pj_w[br * 65536 + n * 256 + k]);
    } else if (i < 786432) {                // Wpin (row-permuted)
        int j = i - 524288;
        int r = j >> 8, k = j & 255;
        int o = (r & 3) * 256 + (r >> 2);
        Wpin[j] = f2bf(pin_w[o * 256 + k]);
    } else if (i < 917504) {                // Wpout
        int j = i - 786432;
        Wpout[j] = f2bf(pout_w[j]);
    } else if (i < 1048576) {               // Wkv0 fp32
        int j = i - 917504;
        int r = j >> 8, k = j & 255;
        Wkv0[j] = (r < 256) ? wk_w[r * 256 + k] : wv_w[(r - 256) * 256 + k];
    } else if (i < 1179648) {               // Wkv1 fp32
        int j = i - 1048576;
        int r = j >> 8, k = j & 255;
        Wkv1[j] = (r < 256) ? wk_w[65536 + r * 256 + k] : wv_w[65536 + (r - 256) * 256 + k];
    } else if (i < 1180928) {               // bias1
        int j = i - 1179648;
        float v;
        if (j < 768)       v = wq_b[j];
        else if (j < 1024) v = wk_b[512 + (j - 768)];
        else               v = wv_b[512 + (j - 1024)];
        bias1[j] = v;
    } else if (i < 1181440) {               // bkv0
        int j = i - 1180928;
        bkv0[j] = (j < 256) ? wk_b[j] : wv_b[j - 256];
    } else if (i < 1181952) {               // bkv1
        int j = i - 1181440;
        bkv1[j] = (j < 256) ? wk_b[256 + j] : wv_b[j];
    }
}

// ------------------------------------------------- 1b. pos conv + LN-gates (wave/token, no barriers)
__global__ __launch_bounds__(256) void k_posgates(
        const float* __restrict__ xT, const float* __restrict__ pw,
        const float* __restrict__ pb, const float* __restrict__ n1w,
        const float* __restrict__ n1b, const float* __restrict__ gw,
        const float* __restrict__ gb, float* __restrict__ feat,
        float* __restrict__ g, short* __restrict__ featb) {
    int wvid = threadIdx.x >> 6;
    int lane = threadIdx.x & 63;
    int c4 = lane * 4;
    float pwv[4][9];
    #pragma unroll
    for (int j = 0; j < 4; j++)
        #pragma unroll
        for (int i = 0; i < 9; i++) pwv[j][i] = pw[(c4 + j) * 9 + i];
    float4 pbv = *(const float4*)(pb + c4);
    float4 w1 = *(const float4*)(n1w + c4);
    float4 b1 = *(const float4*)(n1b + c4);
    float4 gw0 = *(const float4*)(gw + c4);
    float4 gw1 = *(const float4*)(gw + CDIM + c4);
    float4 gw2 = *(const float4*)(gw + 2 * CDIM + c4);
    float gb0 = gb[0], gb1 = gb[1], gb2 = gb[2];
    int tbase = blockIdx.x * 16 + wvid * 4;
    for (int t = 0; t < 4; t++) {
        int bn = tbase + t;
        int b = bn / NQ, n = bn % NQ;
        int y = n / WW, x = n % WW;
        const float* xb = xT + (size_t)b * NQ * CDIM;
        float4 a = *(const float4*)(xb + (size_t)n * CDIM + c4);
        float acc0 = a.x + pbv.x, acc1 = a.y + pbv.y;
        float acc2 = a.z + pbv.z, acc3 = a.w + pbv.w;
        #pragma unroll
        for (int dy = 0; dy < 3; dy++) {
            int yy = y + dy - 1;
            if (yy < 0 || yy >= HH) continue;
            #pragma unroll
            for (int dx = 0; dx < 3; dx++) {
                int xx = x + dx - 1;
                if (xx < 0 || xx >= WW) continue;
                float4 v = *(const float4*)(xb + ((size_t)(yy * WW + xx)) * CDIM + c4);
                int wi = dy * 3 + dx;
                acc0 += v.x * pwv[0][wi];
                acc1 += v.y * pwv[1][wi];
                acc2 += v.z * pwv[2][wi];
                acc3 += v.w * pwv[3][wi];
            }
        }
        *(float4*)(feat + (size_t)bn * CDIM + c4) = make_float4(acc0, acc1, acc2, acc3);
        short4 fb;
        fb.x = f2bf(acc0); fb.y = f2bf(acc1); fb.z = f2bf(acc2); fb.w = f2bf(acc3);
        *(short4*)(featb + (size_t)bn * CDIM + c4) = fb;
        float s = acc0 + acc1 + acc2 + acc3;
        #pragma unroll
        for (int off = 32; off > 0; off >>= 1) s += __shfl_xor(s, off);
        float mu = s * (1.f / CDIM);
        float d0 = acc0 - mu, d1 = acc1 - mu, d2 = acc2 - mu, d3 = acc3 - mu;
        float ss = d0 * d0 + d1 * d1 + d2 * d2 + d3 * d3;
        #pragma unroll
        for (int off = 32; off > 0; off >>= 1) ss += __shfl_xor(ss, off);
        float rstd = rsqrtf(ss * (1.f / CDIM) + 1e-6f);
        float q0 = d0 * rstd * w1.x + b1.x;
        float q1 = d1 * rstd * w1.y + b1.y;
        float q2 = d2 * rstd * w1.z + b1.z;
        float q3 = d3 * rstd * w1.w + b1.w;
        float p0 = q0 * gw0.x + q1 * gw0.y + q2 * gw0.z + q3 * gw0.w;
        float p1 = q0 * gw1.x + q1 * gw1.y + q2 * gw1.z + q3 * gw1.w;
        float p2 = q0 * gw2.x + q1 * gw2.y + q2 * gw2.z + q3 * gw2.w;
        #pragma unroll
        for (int off = 32; off > 0; off >>= 1) {
            p0 += __shfl_xor(p0, off);
            p1 += __shfl_xor(p1, off);
            p2 += __shfl_xor(p2, off);
        }
        if (lane == 0) {
            float l0 = p0 + gb0, l1 = p1 + gb1, l2 = p2 + gb2;
            float m3 = fmaxf(l0, fmaxf(l1, l2));
            float e0 = __expf(l0 - m3), e1 = __expf(l1 - m3), e2 = __expf(l2 - m3);
            float inv = 1.f / (e0 + e1 + e2);
            g[bn * 3 + 0] = e0 * inv;
            g[bn * 3 + 1] = e1 * inv;
            g[bn * 3 + 2] = e2 * inv;
        }
    }
}

// ------------------------------------------------- 2. block means + scores (fused)
__global__ __launch_bounds__(256) void k_blkscore(
        const float* __restrict__ feat, const float* __restrict__ s1w,
        const float* __restrict__ s1b, const float* __restrict__ s2w,
        const float* __restrict__ s2b, float* __restrict__ blk,
        float* __restrict__ scores) {
    __shared__ float sblk[256];
    __shared__ float red[128];
    int gid = blockIdx.x;
    int b = gid / NB, bid = gid % NB;
    int by = bid / 7, bx = bid % 7;
    int c = threadIdx.x;
    float s = 0.f;
    for (int iy = 0; iy < 8; iy++)
        for (int ix = 0; ix < 8; ix++) {
            int y = by * 8 + iy, xx = bx * 8 + ix;
            s += feat[((size_t)(b * NQ + y * WW + xx)) * CDIM + c];
        }
    s *= (1.f / 64.f);
    blk[(size_t)gid * CDIM + c] = s;
    sblk[c] = s;
    __syncthreads();
    if (c < 128) {
        const float* wrow = s1w + (size_t)c * CDIM;
        float acc = s1b[c];
        for (int k = 0; k < CDIM; k++) acc += sblk[k] * wrow[k];
        red[c] = gelu_exact(acc) * s2w[c];
    }
    __syncthreads();
    #pragma unroll
    for (int st = 64; st > 0; st >>= 1) {
        if (c < st) red[c] += red[c + st];
        __syncthreads();
    }
    if (c == 0) scores[gid] = red[0] + s2b[0];
}

// ------------------------------------------------- merged: QKV MFMA GEMM (blocks<980) + kv fp32 GEMM (blocks>=980)
__global__ __launch_bounds__(256) void k_qkvkv(
        const short* __restrict__ A, const short* __restrict__ W,
        const float* __restrict__ bias, _Float16* __restrict__ C2,
        const float* __restrict__ blk, const float* __restrict__ Wkv0,
        const float* __restrict__ bkv0, _Float16* __restrict__ kvcmp,
        const float* __restrict__ scores, const float* __restrict__ Wkv1,
        const float* __restrict__ bkv1, _Float16* __restrict__ kvsel) {
    __shared__ __align__(16) char sm[27648];
    int bid = blockIdx.x;
    int tid = threadIdx.x;
    if (bid < 980) {
        const int K = 256, N = 1280;
        short (*As)[72] = (short(*)[72])sm;
        short (*Bs)[72] = (short(*)[72])(sm + 64 * 72 * 2);
        int wid = tid >> 6, lane = tid & 63;
        int wm = wid >> 1, wn = wid & 1;
        int m0 = (bid / 10) * 64, n0 = (bid % 10) * 128;
        f32x4 acc[2][4] = {};
        int ar = tid >> 2, ac = (tid & 3) * 16;
        int br = tid >> 1, bc = (tid & 1) * 32;
        int fr = lane & 15, fk = (lane >> 4) * 8;
        for (int k0 = 0; k0 < K; k0 += 64) {
            const short* ap = A + (size_t)(m0 + ar) * K + k0 + ac;
            bf16x8 a0 = *(const bf16x8*)(ap);
            bf16x8 a1 = *(const bf16x8*)(ap + 8);
            const short* wp = W + (size_t)(n0 + br) * K + k0 + bc;
            bf16x8 w0 = *(const bf16x8*)(wp);
            bf16x8 w1 = *(const bf16x8*)(wp + 8);
            bf16x8 w2 = *(const bf16x8*)(wp + 16);
            bf16x8 w3 = *(const bf16x8*)(wp + 24);
            __syncthreads();
            *(bf16x8*)&As[ar][ac] = a0;
            *(bf16x8*)&As[ar][ac + 8] = a1;
            *(bf16x8*)&Bs[br][bc] = w0;
            *(bf16x8*)&Bs[br][bc + 8] = w1;
            *(bf16x8*)&Bs[br][bc + 16] = w2;
            *(bf16x8*)&Bs[br][bc + 24] = w3;
            __syncthreads();
            #pragma unroll
            for (int kk = 0; kk < 64; kk += 32) {
                bf16x8 af[2], bf[4];
                #pragma unroll
                for (int mi = 0; mi < 2; mi++)
                    af[mi] = *(const bf16x8*)&As[wm * 32 + mi * 16 + fr][kk + fk];
                #pragma unroll
                for (int ni = 0; ni < 4; ni++)
                    bf[ni] = *(const bf16x8*)&Bs[wn * 64 + ni * 16 + fr][kk + fk];
                #pragma unroll
                for (int mi = 0; mi < 2; mi++)
                    #pragma unroll
                    for (int ni = 0; ni < 4; ni++)
                        acc[mi][ni] = __builtin_amdgcn_mfma_f32_16x16x32_bf16(
                            af[mi], bf[ni], acc[mi][ni], 0, 0, 0);
            }
        }
        int rsub = (lane >> 4) * 4;
        #pragma unroll
        for (int mi = 0; mi < 2; mi++) {
            #pragma unroll
            for (int ni = 0; ni < 4; ni++) {
                int col = n0 + wn * 64 + ni * 16 + (lane & 15);
                float bv = bias[col];
                #pragma unroll
                for (int r = 0; r < 4; r++) {
                    int row = m0 + wm * 32 + mi * 16 + rsub + r;
                    C2[(size_t)row * N + col] = (_Float16)(acc[mi][ni][r] + bv);
                }
            }
        }
    } else {
        float (*As)[68] = (float(*)[68])sm;
        float (*Ws)[68] = (float(*)[68])(sm + 16 * 68 * 4);
        float (*ssc)[NB] = (float(*)[NB])(sm + 2 * 16 * 68 * 4);
        int* sidx = (int*)(sm + 2 * 16 * 68 * 4 + 2 * NB * 4);
        int kid = bid - 980;
        int kvy = kid >> 3, kvx = kid & 7;
        const float* Wk; const float* biask; _Float16* C; int M;
        int m0;
        bool sel = (kvy == 2);
        if (!sel) { Wk = Wkv0; biask = bkv0; C = kvcmp; M = 98; m0 = kvy * 64; }
        else      { Wk = Wkv1; biask = bkv1; C = kvsel; M = 8;  m0 = 0; }
        const int N = 512, K = 256;
        const int tx = tid & 15, ty = tid >> 4;
        const int n0 = kvx * 64;
        const int lr = tid >> 2;
        const int lk = (tid & 3) * 4;
        if (sel) {
            if (tid < 2 * NB) ssc[tid / NB][tid % NB] = scores[tid];
            __syncthreads();
            if (tid < 2) {
                for (int t = 0; t < NTOPK; t++) {
                    int best = 0; float bv = -1e30f;
                    for (int m = 0; m < NB; m++)
                        if (ssc[tid][m] > bv) { bv = ssc[tid][m]; best = m; }
                    sidx[tid * 4 + t] = best; ssc[tid][best] = -1e30f;
                }
            }
            __syncthreads();
        }
        int gm = m0 + lr;
        int arow = gm;
        if (sel && gm < 8) arow = (gm >> 2) * NB + sidx[gm];
        float acc[4][4] = {};
        for (int k0 = 0; k0 < K; k0 += 16) {
            float4 av = make_float4(0.f, 0.f, 0.f, 0.f);
            if (gm < M) av = *(const float4*)(blk + (size_t)arow * K + k0 + lk);
            int gn = n0 + lr;
            float4 wv = *(const float4*)(Wk + (size_t)gn * K + k0 + lk);
            __syncthreads();
            As[lk][lr] = av.x; As[lk + 1][lr] = av.y; As[lk + 2][lr] = av.z; As[lk + 3][lr] = av.w;
            Ws[lk][lr] = wv.x; Ws[lk + 1][lr] = wv.y; Ws[lk + 2][lr] = wv.z; Ws[lk + 3][lr] = wv.w;
            __syncthreads();
            #pragma unroll
            for (int kk = 0; kk < 16; kk++) {
                const float4 a = *(const float4*)&As[kk][ty * 4];
                const float4 b = *(const float4*)&Ws[kk][tx * 4];
                acc[0][0] += a.x * b.x; acc[0][1] += a.x * b.y; acc[0][2] += a.x * b.z; acc[0][3] += a.x * b.w;
                acc[1][0] += a.y * b.x; acc[1][1] += a.y * b.y; acc[1][2] += a.y * b.z; acc[1][3] += a.y * b.w;
                acc[2][0] += a.z * b.x; acc[2][1] += a.z * b.y; acc[2][2] += a.z * b.z; acc[2][3] += a.z * b.w;
                acc[3][0] += a.w * b.x; acc[3][1] += a.w * b.y; acc[3][2] += a.w * b.z; acc[3][3] += a.w * b.w;
            }
        }
        #pragma unroll
        for (int i = 0; i < 4; i++) {
            int om = m0 + ty * 4 + i;
            if (om >= M) break;
            #pragma unroll
            for (int j = 0; j < 4; j++) {
                int gn = n0 + tx * 4 + j;
                C[(size_t)om * N + gn] = (_Float16)(acc[i][j] + biask[gn]);
            }
        }
    }
}

// ------------------------------------------------- MFMA GEMM 64x128, BK=64, bf16 A, f16 out
__global__ __launch_bounds__(256) void k_gemm64x128(
        const short* __restrict__ A, const short* __restrict__ W,
        const float* __restrict__ bias, int M, int N, int K,
        _Float16* __restrict__ C2) {
    __shared__ short As[64][72];
    __shared__ short Bs[128][72];
    int tid = threadIdx.x;
    int wid = tid >> 6, lane = tid & 63;
    int wm = wid >> 1, wn = wid & 1;
    int m0 = blockIdx.y * 64, n0 = blockIdx.x * 128;
    f32x4 acc[2][4] = {};
    int ar = tid >> 2, ac = (tid & 3) * 16;
    int br = tid >> 1, bc = (tid & 1) * 32;
    int fr = lane & 15, fk = (lane >> 4) * 8;
    for (int k0 = 0; k0 < K; k0 += 64) {
        const short* ap = A + (size_t)(m0 + ar) * K + k0 + ac;
        bf16x8 a0 = *(const bf16x8*)(ap);
        bf16x8 a1 = *(const bf16x8*)(ap + 8);
        const short* wp = W + (size_t)(n0 + br) * K + k0 + bc;
        bf16x8 w0 = *(const bf16x8*)(wp);
        bf16x8 w1 = *(const bf16x8*)(wp + 8);
        bf16x8 w2 = *(const bf16x8*)(wp + 16);
        bf16x8 w3 = *(const bf16x8*)(wp + 24);
        __syncthreads();
        *(bf16x8*)&As[ar][ac] = a0;
        *(bf16x8*)&As[ar][ac + 8] = a1;
        *(bf16x8*)&Bs[br][bc] = w0;
        *(bf16x8*)&Bs[br][bc + 8] = w1;
        *(bf16x8*)&Bs[br][bc + 16] = w2;
        *(bf16x8*)&Bs[br][bc + 24] = w3;
        __syncthreads();
        #pragma unroll
        for (int kk = 0; kk < 64; kk += 32) {
            bf16x8 af[2], bf[4];
            #pragma unroll
            for (int mi = 0; mi < 2; mi++)
                af[mi] = *(const bf16x8*)&As[wm * 32 + mi * 16 + fr][kk + fk];
            #pragma unroll
            for (int ni = 0; ni < 4; ni++)
                bf[ni] = *(const bf16x8*)&Bs[wn * 64 + ni * 16 + fr][kk + fk];
            #pragma unroll
            for (int mi = 0; mi < 2; mi++)
                #pragma unroll
                for (int ni = 0; ni < 4; ni++)
                    acc[mi][ni] = __builtin_amdgcn_mfma_f32_16x16x32_bf16(
                        af[mi], bf[ni], acc[mi][ni], 0, 0, 0);
        }
    }
    int rsub = (lane >> 4) * 4;
    #pragma unroll
    for (int mi = 0; mi < 2; mi++) {
        #pragma unroll
        for (int ni = 0; ni < 4; ni++) {
            int col = n0 + wn * 64 + ni * 16 + (lane & 15);
            float bv = bias ? bias[col] : 0.f;
            #pragma unroll
            for (int r = 0; r < 4; r++) {
                int row = m0 + wm * 32 + mi * 16 + rsub + r;
                C2[(size_t)row * N + col] = (_Float16)(acc[mi][ni][r] + bv);
            }
        }
    }
}

// ------------------------------------------------- MFMA GEMM 64x64, BK=64, bf16 A (resid epi)
__global__ __launch_bounds__(256) void k_gemm64(
        const short* __restrict__ A, const short* __restrict__ W,
        const float* __restrict__ bias, float* __restrict__ C,
        int M, int N, int K,
        const float* __restrict__ resid, const float* __restrict__ g3,
        const float* __restrict__ pjb, short* __restrict__ Cb) {
    __shared__ short As[64][72];
    __shared__ short Bs[64][72];
    int tid = threadIdx.x;
    int wid = tid >> 6, lane = tid & 63;
    int wm = wid >> 1, wn = wid & 1;
    int m0 = blockIdx.y * 64, n0 = blockIdx.x * 64;
    f32x4 acc[2][2] = {};
    int ar = tid >> 2, ac = (tid & 3) * 16;
    int fr = lane & 15, fk = (lane >> 4) * 8;
    for (int k0 = 0; k0 < K; k0 += 64) {
        const short* ap = A + (size_t)(m0 + ar) * K + k0 + ac;
        bf16x8 a0 = *(const bf16x8*)(ap);
        bf16x8 a1 = *(const bf16x8*)(ap + 8);
        const short* wp = W + (size_t)(n0 + ar) * K + k0 + ac;
        bf16x8 w0 = *(const bf16x8*)(wp);
        bf16x8 w1 = *(const bf16x8*)(wp + 8);
        __syncthreads();
        *(bf16x8*)&As[ar][ac] = a0;
        *(bf16x8*)&As[ar][ac + 8] = a1;
        *(bf16x8*)&Bs[ar][ac] = w0;
        *(bf16x8*)&Bs[ar][ac + 8] = w1;
        __syncthreads();
        #pragma unroll
        for (int kk = 0; kk < 64; kk += 32) {
            bf16x8 af[2], bf[2];
            #pragma unroll
            for (int mi = 0; mi < 2; mi++)
                af[mi] = *(const bf16x8*)&As[wm * 32 + mi * 16 + fr][kk + fk];
            #pragma unroll
            for (int ni = 0; ni < 2; ni++)
                bf[ni] = *(const bf16x8*)&Bs[wn * 32 + ni * 16 + fr][kk + fk];
            #pragma unroll
            for (int mi = 0; mi < 2; mi++)
                #pragma unroll
                for (int ni = 0; ni < 2; ni++)
                    acc[mi][ni] = __builtin_amdgcn_mfma_f32_16x16x32_bf16(
                        af[mi], bf[ni], acc[mi][ni], 0, 0, 0);
        }
    }
    int rsub = (lane >> 4) * 4;
    #pragma unroll
    for (int mi = 0; mi < 2; mi++) {
        #pragma unroll
        for (int ni = 0; ni < 2; ni++) {
            int col = n0 + wn * 32 + ni * 16 + (lane & 15);
            #pragma unroll
            for (int r = 0; r < 4; r++) {
                int row = m0 + wm * 32 + mi * 16 + rsub + r;
                float v = acc[mi][ni][r];
                if (resid) {
                    v += resid[(size_t)row * N + col]
                       + g3[row * 3 + 0] * pjb[col]
                       + g3[row * 3 + 1] * pjb[256 + col]
                       + g3[row * 3 + 2] * pjb[512 + col];
                } else if (bias) {
                    v += bias[col];
                }
                C[(size_t)row * N + col] = v;
                if (Cb) Cb[(size_t)row * N + col] = f2bf(v);
            }
        }
    }
}

// ------------------------------------------------- pout GEMM + final LN + NCHW write (fused)
__global__ __launch_bounds__(256) void k_poutln(
        const short* __restrict__ G, const short* __restrict__ W,
        const float* __restrict__ ym, const float* __restrict__ n2w,
        const float* __restrict__ n2b, float* __restrict__ out) {
    __shared__ short As[32][72];
    __shared__ float redS[4][36];
    __shared__ float redQ[4][36];
    int tid = threadIdx.x;
    int wid = tid >> 6, lane = tid & 63;
    int bx = blockIdx.x;
    int b = bx / 98;
    int t0g = bx * 32;                 // global token base
    int p0 = (bx % 98) * 32;           // pixel base within batch
    f32x4 acc[2][4] = {};
    int ar = tid >> 3, ac = (tid & 7) * 8;
    int fr = lane & 15, fk = (lane >> 4) * 8;
    const short* Wb = W + (size_t)(wid * 64) * 512;
    for (int k0 = 0; k0 < 512; k0 += 64) {
        bf16x8 a0 = *(const bf16x8*)(G + (size_t)(t0g + ar) * 512 + k0 + ac);
        __syncthreads();
        *(bf16x8*)&As[ar][ac] = a0;
        __syncthreads();
        #pragma unroll
        for (int kk = 0; kk < 64; kk += 32) {
            bf16x8 af[2], bf[4];
            #pragma unroll
            for (int mi = 0; mi < 2; mi++)
                af[mi] = *(const bf16x8*)&As[mi * 16 + fr][kk + fk];
            #pragma unroll
            for (int ni = 0; ni < 4; ni++)
                bf[ni] = *(const bf16x8*)(Wb + (size_t)(ni * 16 + fr) * 512 + k0 + kk + fk);
            #pragma unroll
            for (int mi = 0; mi < 2; mi++)
                #pragma unroll
                for (int ni = 0; ni < 4; ni++)
                    acc[mi][ni] = __builtin_amdgcn_mfma_f32_16x16x32_bf16(
                        af[mi], bf[ni], acc[mi][ni], 0, 0, 0);
        }
    }
    int rsub = (lane >> 4) * 4;
    float v[2][4][4];
    #pragma unroll
    for (int mi = 0; mi < 2; mi++)
        #pragma unroll
        for (int ni = 0; ni < 4; ni++) {
            int col = wid * 64 + ni * 16 + fr;
            #pragma unroll
            for (int r = 0; r < 4; r++) {
                int row = mi * 16 + rsub + r;
                v[mi][ni][r] = acc[mi][ni][r] + ym[(size_t)(t0g + row) * CDIM + col];
            }
        }
    #pragma unroll
    for (int mi = 0; mi < 2; mi++) {
        #pragma unroll
        for (int r = 0; r < 4; r++) {
            float s = v[mi][0][r] + v[mi][1][r] + v[mi][2][r] + v[mi][3][r];
            s += __shfl_xor(s, 1); s += __shfl_xor(s, 2);
            s += __shfl_xor(s, 4); s += __shfl_xor(s, 8);
            if (fr == 0) redS[wid][mi * 16 + rsub + r] = s;
        }
    }
    __syncthreads();
    float mu[2][4];
    #pragma unroll
    for (int mi = 0; mi < 2; mi++)
        #pragma unroll
        for (int r = 0; r < 4; r++) {
            int row = mi * 16 + rsub + r;
            mu[mi][r] = (redS[0][row] + redS[1][row] + redS[2][row] + redS[3][row])
                        * (1.f / CDIM);
        }
    #pragma unroll
    for (int mi = 0; mi < 2; mi++) {
        #pragma unroll
        for (int r = 0; r < 4; r++) {
            float m = mu[mi][r];
            float d0 = v[mi][0][r] - m, d1 = v[mi][1][r] - m;
            float d2 = v[mi][2][r] - m, d3 = v[mi][3][r] - m;
            float q = d0 * d0 + d1 * d1 + d2 * d2 + d3 * d3;
            q += __shfl_xor(q, 1); q += __shfl_xor(q, 2);
            q += __shfl_xor(q, 4); q += __shfl_xor(q, 8);
            if (fr == 0) redQ[wid][mi * 16 + rsub + r] = q;
        }
    }
    __syncthreads();
    float rstd[2][4];
    #pragma unroll
    for (int mi = 0; mi < 2; mi++)
        #pragma unroll
        for (int r = 0; r < 4; r++) {
            int row = mi * 16 + rsub + r;
            float var = (redQ[0][row] + redQ[1][row] + redQ[2][row] + redQ[3][row])
                        * (1.f / CDIM);
            rstd[mi][r] = rsqrtf(var + 1e-6f);
        }
    #pragma unroll
    for (int mi = 0; mi < 2; mi++) {
        #pragma unroll
        for (int ni = 0; ni < 4; ni++) {
            int col = wid * 64 + ni * 16 + fr;
            float wgt = n2w[col], bia = n2b[col];
            float4 o;
            o.x = (v[mi][ni][0] - mu[mi][0]) * rstd[mi][0] * wgt + bia;
            o.y = (v[mi][ni][1] - mu[mi][1]) * rstd[mi][1] * wgt + bia;
            o.z = (v[mi][ni][2] - mu[mi][2]) * rstd[mi][2] * wgt + bia;
            o.w = (v[mi][ni][3] - mu[mi][3]) * rstd[mi][3] * wgt + bia;
            *(float4*)(out + ((size_t)(b * CDIM + col)) * NQ + p0 + mi * 16 + rsub) = o;
        }
    }
}

// ------------------------------------------------- fused attention, f16 LDS-staged K/V
// 512 threads, 16 tokens/block.  blocks [0,392): cmp+sel — K AND V staged
// up-front into disjoint slots (K->0..48, V->49..97), ONE barrier total.
// [392,784): window (4x4 token tile, 10x10 px union), unchanged 3-barrier.
__global__ __launch_bounds__(512) void k_attn_lds(
        const _Float16* __restrict__ bufQ, const _Float16* __restrict__ kvc,
        const _Float16* __restrict__ kvs, short* __restrict__ Acatb,
        const float* __restrict__ g) {
    __shared__ uint4 buf[100 * 32];       // 51.2 KB
    int tid = threadIdx.x;
    int wid = tid >> 6;                   // 0..7
    int lane = tid & 63;
    int l = tid & 31;                     // lane within token group
    int tk = tid >> 5;                    // token 0..15 within block
    int dg = l & 3;
    int co = l * 8;                       // channel offset
    const float scale = 0.17677669529663687f;

    if (blockIdx.x < 392) {
        // ======================= cmp + sel =======================
        int bid = blockIdx.x;
        int swz = (bid & 7) * 49 + (bid >> 3);    // bijective XCD swizzle (392=8*49)
        int t0 = swz * 16;
        int tok = t0 + tk;
        int b = t0 / NQ;
        const _Float16* kb = kvc + (size_t)b * NB * 512;
        // ---- stage K (slots 0..48) AND V (slots 49..97) up-front ----
        for (int p = wid * 2; p < 98; p += 16) {
            int slot = p + (lane >> 5);
            int px = (slot < NB) ? slot : slot - NB;
            int off = (slot < NB) ? 0 : 256;
            gld16((const uint4*)(kb + (size_t)px * 512 + off) + (lane & 31), &buf[p * 32]);
        }
        const _Float16* qrow = bufQ + (size_t)tok * QSTRH;
        float gate0 = g[tok * 3 + 0];
        float gate1 = g[tok * 3 + 1];
        short* orow = Acatb + (size_t)tok * ASTR;
        h2x4 qv = *(const h2x4*)(qrow + co);
        __syncthreads();                  // K+V staged (single barrier)
        // ---- cmp scores from LDS ----
        float sc[13];
        sc[12] = -1e30f;
        #pragma unroll
        for (int m = 0; m < NB; m++) {
            h2x4 kv = *(const h2x4*)&buf[m * 32 + l];
            float acc = fdot2h(qv.x, kv.x, 0.f);
            acc = fdot2h(qv.y, kv.y, acc);
            acc = fdot2h(qv.z, kv.z, acc);
            acc = fdot2h(qv.w, kv.w, acc);
            acc += __shfl_xor(acc, 1);
            acc += __shfl_xor(acc, 2);
            if ((m & 3) == dg) sc[m >> 2] = acc * scale;
        }
        float mx = sc[0];
        #pragma unroll
        for (int i = 1; i < 13; i++) mx = fmaxf(mx, sc[i]);
        mx = fmaxf(mx, __shfl_xor(mx, 1));
        mx = fmaxf(mx, __shfl_xor(mx, 2));
        float sum = 0.f;
        #pragma unroll
        for (int i = 0; i < 13; i++) { sc[i] = __expf(sc[i] - mx); sum += sc[i]; }
        sum += __shfl_xor(sum, 1);
        sum += __shfl_xor(sum, 2);
        float inv_c = 1.f / sum;
        // ---- sel branch (kvsel f16, L1/L2-resident: global) ----
        {
            const _Float16* ksb = kvs + (size_t)b * NTOPK * 512;
            h2x4 qs = *(const h2x4*)(qrow + 256 + co);
            float sv = 0.f;
            #pragma unroll
            for (int m = 0; m < NTOPK; m++) {
                h2x4 kk = *(const h2x4*)(ksb + (size_t)m * 512 + co);
                float acc = fdot2h(qs.x, kk.x, 0.f);
                acc = fdot2h(qs.y, kk.y, acc);
                acc = fdot2h(qs.z, kk.z, acc);
                acc = fdot2h(qs.w, kk.w, acc);
                acc += __shfl_xor(acc, 1);
                acc += __shfl_xor(acc, 2);
                if (m == dg) sv = acc * scale;
            }
            float mxs = sv;
            mxs = fmaxf(mxs, __shfl_xor(mxs, 1));
            mxs = fmaxf(mxs, __shfl_xor(mxs, 2));
            float e = __expf(sv - mxs);
            float sums = e;
            sums += __shfl_xor(sums, 1);
            sums += __shfl_xor(sums, 2);
            float invs = 1.f / sums;
            float o[8];
            #pragma unroll
            for (int d = 0; d < 8; d++) o[d] = 0.f;
            #pragma unroll
            for (int m = 0; m < NTOPK; m++) {
                float pw = __shfl(e, m, 4);
                h2x4 vv = *(const h2x4*)(ksb + (size_t)m * 512 + 256 + co);
                o[0] += pw * (float)vv.x[0]; o[1] += pw * (float)vv.x[1];
                o[2] += pw * (float)vv.y[0]; o[3] += pw * (float)vv.y[1];
                o[4] += pw * (float)vv.z[0]; o[5] += pw * (float)vv.z[1];
                o[6] += pw * (float)vv.w[0]; o[7] += pw * (float)vv.w[1];
            }
            float gg = gate1 * invs;
            bf16x8 ov;
            #pragma unroll
            for (int d = 0; d < 8; d++) ov[d] = f2bf(o[d] * gg);
            *(bf16x8*)(orow + 256 + co) = ov;
        }
        // ---- cmp PV from LDS (V slots 49..97; no barrier needed) ----
        {
            float o[8];
            #pragma unroll
            for (int d = 0; d < 8; d++) o[d] = 0.f;
            #pragma unroll
            for (int m = 0; m < NB; m++) {
                float pw = __shfl(sc[m >> 2], m & 3, 4);
                h2x4 vv = *(const h2x4*)&buf[(NB + m) * 32 + l];
                o[0] += pw * (float)vv.x[0]; o[1] += pw * (float)vv.x[1];
                o[2] += pw * (float)vv.y[0]; o[3] += pw * (float)vv.y[1];
                o[4] += pw * (float)vv.z[0]; o[5] += pw * (float)vv.z[1];
                o[6] += pw * (float)vv.w[0]; o[7] += pw * (float)vv.w[1];
            }
            float gg = gate0 * inv_c;
            bf16x8 ov;
            #pragma unroll
            for (int d = 0; d < 8; d++) ov[d] = f2bf(o[d] * gg);
            *(bf16x8*)(orow + co) = ov;
        }
    } else {
        // ======================= window (4x4 tile) =======================
        int bid = blockIdx.x - 392;
        int swz = (bid & 7) * 49 + (bid >> 3);
        int b = swz / 196;
        int r = swz % 196;
        int y0 = (r / 14) * 4;
        int x0 = (r % 14) * 4;
        int ty = tk >> 2, tx = tk & 3;
        int y = y0 + ty, x = x0 + tx;
        int tok = b * NQ + y * WW + x;
        const _Float16* KVb = bufQ + (size_t)b * NQ * QSTRH;
        for (int p = wid * 2; p < 100; p += 16) {
            int pp = p + (lane >> 5);
            int pr = pp / 10, pc = pp - pr * 10;
            int gy = min(max(y0 + pr - 3, 0), HH - 1);
            int gx = min(max(x0 + pc - 3, 0), WW - 1);
            gld16((const uint4*)(KVb + (size_t)(gy * WW + gx) * QSTRH + 768) + (lane & 31),
                  &buf[p * 32]);
        }
        h2x4 qv = *(const h2x4*)(bufQ + (size_t)tok * QSTRH + 512 + co);
        float gate = g[tok * 3 + 2];
        __syncthreads();                  // K staged
        float sw[13];
        sw[12] = -1e30f;
        #pragma unroll
        for (int dy = 0; dy < 7; dy++) {
            #pragma unroll
            for (int dx = 0; dx < 7; dx++) {
                int p = (ty + dy) * 10 + tx + dx;
                h2x4 kv = *(const h2x4*)&buf[p * 32 + l];
                float acc = fdot2h(qv.x, kv.x, 0.f);
                acc = fdot2h(qv.y, kv.y, acc);
                acc = fdot2h(qv.z, kv.z, acc);
                acc = fdot2h(qv.w, kv.w, acc);
                acc += __shfl_xor(acc, 1);
                acc += __shfl_xor(acc, 2);
                int m = dy * 7 + dx;
                if ((m & 3) == dg) sw[m >> 2] = acc * scale;
            }
        }
        float mx = sw[0];
        #pragma unroll
        for (int i = 1; i < 13; i++) mx = fmaxf(mx, sw[i]);
        mx = fmaxf(mx, __shfl_xor(mx, 1));
        mx = fmaxf(mx, __shfl_xor(mx, 2));
        float sum = 0.f;
        #pragma unroll
        for (int i = 0; i < 13; i++) { sw[i] = __expf(sw[i] - mx); sum += sw[i]; }
        sum += __shfl_xor(sum, 1);
        sum += __shfl_xor(sum, 2);
        float inv = 1.f / sum;
        __syncthreads();                  // all waves done reading K
        for (int p = wid * 2; p < 100; p += 16) {
            int pp = p + (lane >> 5);
            int pr = pp / 10, pc = pp - pr * 10;
            int gy = min(max(y0 + pr - 3, 0), HH - 1);
            int gx = min(max(x0 + pc - 3, 0), WW - 1);
            gld16((const uint4*)(KVb + (size_t)(gy * WW + gx) * QSTRH + 1024) + (lane & 31),
                  &buf[p * 32]);
        }
        __syncthreads();                  // V staged
        float o[8];
        #pragma unroll
        for (int d = 0; d < 8; d++) o[d] = 0.f;
        #pragma unroll
        for (int dy = 0; dy < 7; dy++) {
            #pragma unroll
            for (int dx = 0; dx < 7; dx++) {
                int p = (ty + dy) * 10 + tx + dx;
                int m = dy * 7 + dx;
                float pw = __shfl(sw[m >> 2], m & 3, 4);
                h2x4 vv = *(const h2x4*)&buf[p * 32 + l];
                o[0] += pw * (float)vv.x[0]; o[1] += pw * (float)vv.x[1];
                o[2] += pw * (float)vv.y[0]; o[3] += pw * (float)vv.y[1];
                o[4] += pw * (float)vv.z[0]; o[5] += pw * (float)vv.z[1];
                o[6] += pw * (float)vv.w[0]; o[7] += pw * (float)vv.w[1];
            }
        }
        float gg = gate * inv;
        short* op = Acatb + (size_t)tok * ASTR + 512 + co;
        bf16x8 ov;
        #pragma unroll
        for (int d = 0; d < 8; d++) ov[d] = f2bf(o[d] * gg);
        *(bf16x8*)(op) = ov;
    }
}

// ------------------------------------------------- dwconv 3x3 + GLU (2 y-rows/block, h4 loads)
__global__ __launch_bounds__(256) void k_dwglu2(
        const _Float16* __restrict__ t, const float* __restrict__ w,
        short* __restrict__ G) {
    int gid = blockIdx.x;
    int xq = gid & 7;                 // 8 chunks of 7 pixels
    int y0 = ((gid >> 3) % (HH / 2)) * 2;
    int b = gid / ((HH / 2) * 8);
    int c = threadIdx.x;
    float wv[9][4];
    #pragma unroll
    for (int i = 0; i < 9; i++)
        #pragma unroll
        for (int j = 0; j < 4; j++) wv[i][j] = w[i * HID2 + j * 256 + c];
    const _Float16* tb = t + (size_t)b * NQ * HID2;
    short* Gbase = G + (size_t)b * NQ * HIDM;
    int x0 = xq * 7;
    float col[3][4][4];               // [xslot][row y0-1..y0+2][j]
    #pragma unroll
    for (int ci = 0; ci < 2; ci++) {
        int xx = x0 - 1 + ci;
        #pragma unroll
        for (int r = 0; r < 4; r++) {
            int yy = y0 + r - 1;
            bool ok = (xx >= 0) && (yy >= 0) && (yy < HH);
            h4 v = {};
            if (ok) v = *(const h4*)(tb + ((size_t)(yy * WW + xx)) * HID2 + c * 4);
            #pragma unroll
            for (int j = 0; j < 4; j++) col[ci][r][j] = (float)v[j];
        }
    }
    #pragma unroll
    for (int i = 0; i < 7; i++) {
        int xx = x0 + i;
        {
            int xl = xx + 1;
            #pragma unroll
            for (int r = 0; r < 4; r++) {
                int yy = y0 + r - 1;
                bool ok = (xl < WW) && (yy >= 0) && (yy < HH);
                h4 v = {};
                if (ok) v = *(const h4*)(tb + ((size_t)(yy * WW + xl)) * HID2 + c * 4);
                #pragma unroll
                for (int j = 0; j < 4; j++) col[(i + 2) % 3][r][j] = (float)v[j];
            }
        }
        #pragma unroll
        for (int o = 0; o < 2; o++) {
            float a0 = 0.f, a1 = 0.f, a2 = 0.f, a3 = 0.f;
            #pragma unroll
            for (int r = 0; r < 3; r++) {
                #pragma unroll
                for (int dxx = 0; dxx < 3; dxx++) {
                    const float* cc = col[(i + dxx) % 3][r + o];
                    int wi = r * 3 + dxx;
                    a0 += cc[0] * wv[wi][0];
                    a1 += cc[1] * wv[wi][1];
                    a2 += cc[2] * wv[wi][2];
                    a3 += cc[3] * wv[wi][3];
                }
            }
            short* Gb = Gbase + (size_t)((y0 + o) * WW + xx) * HIDM;
            Gb[c]       = f2bf(gelu_exact(a0) * a2);
            Gb[c + 256] = f2bf(gelu_exact(a1) * a3);
        }
    }
}

// ================================================================ host
extern "C" void kernel_launch(void* const* d_in, const int* in_sizes, int n_in,
                              void* d_out, int out_size, void* d_ws, size_t ws_size,
                              hipStream_t stream) {
    const float* x     = (const float*)d_in[0];
    const float* pos_w = (const float*)d_in[1];
    const float* pos_b = (const float*)d_in[2];
    const float* n1w   = (const float*)d_in[3];
    const float* n1b   = (const float*)d_in[4];
    const float* n2w   = (const float*)d_in[5];
    const float* n2b   = (const float*)d_in[6];
    const float* wq_w  = (const float*)d_in[7];
    const float* wq_b  = (const float*)d_in[8];
    const float* wk_w  = (const float*)d_in[9];
    const float* wk_b  = (const float*)d_in[10];
    const float* wv_w  = (const float*)d_in[11];
    const float* wv_b  = (const float*)d_in[12];
    const float* pj_w  = (const float*)d_in[13];
    const float* pj_b  = (const float*)d_in[14];
    const float* s1w   = (const float*)d_in[15];
    const float* s1b   = (const float*)d_in[16];
    const float* s2w   = (const float*)d_in[17];
    const float* s2b   = (const float*)d_in[18];
    const float* gw    = (const float*)d_in[19];
    const float* gb    = (const float*)d_in[20];
    const float* pinw  = (const float*)d_in[21];
    const float* dww   = (const float*)d_in[22];
    const float* poutw = (const float*)d_in[23];
    float* out = (float*)d_out;
    float* ws  = (float*)d_ws;

    const size_t SZ = (size_t)NTOK * CDIM;
    float* feat = ws;                               // [NTOK,256] fp32
    _Float16* bufQh = (_Float16*)(feat + SZ);       // [NTOK,1280] f16 (q0|q1|q2|kw|vw)
    float* R1   = (float*)(bufQh + (size_t)NTOK * QSTRH);  // xT / Acatb / T1h share
    float* xT   = R1;                               // [NTOK,256] fp32
    short* Acatb = (short*)R1;                      // [NTOK,768] bf16
    _Float16* T1h = (_Float16*)R1;                  // [NTOK,1024] f16 (permuted channels)
    float* ym   = R1 + (size_t)NTOK * 512;          // [NTOK,256] fp32
    short* featb = (short*)(ym + SZ);               // [NTOK,256] bf16
    short* ymb   = featb + (size_t)NTOK * CDIM;     // [NTOK,256] bf16
    float* blk   = (float*)(ymb + (size_t)NTOK * CDIM);  // [98,256] fp32
    _Float16* kvcmp = (_Float16*)(blk + 98 * 256);  // [98,512] f16
    _Float16* kvsel = kvcmp + 98 * 512;             // [8,512] f16
    float* scores = (float*)(kvsel + 8 * 512);      // [128]
    float* g      = scores + 128;                   // [NTOK,3]
    float* bias1  = g + (size_t)NTOK * 3;           // [1280]
    float* Wkv0   = bias1 + 1280;                   // [512,256] fp32
    float* bkv0   = Wkv0 + 512 * 256;
    float* Wkv1   = bkv0 + 512;
    float* bkv1   = Wkv1 + 512 * 256;
    short* Wc1    = (short*)(bkv1 + 512);           // bf16 [1280,256]
    short* Wpj    = Wc1 + 1280 * 256;               // bf16 [256,768]
    short* Wpin   = Wpj + 256 * 768;                // bf16 [1024,256] (row-permuted)
    short* Wpout  = Wpin + 1024 * 256;              // bf16 [256,512]
    short* G      = (short*)bufQh;                  // alias [NTOK,512] bf16 (bufQh dead after attn)

    // merged transpose + weight convert (independent work, one launch)
    hipLaunchKernelGGL(k_init, dim3(392 + 4618), dim3(256), 0, stream,
                       x, xT, wq_w, wk_w, wv_w, wq_b, wk_b, wv_b, pj_w, pinw, poutw,
                       Wc1, Wpj, Wpin, Wpout, bias1, Wkv0, bkv0, Wkv1, bkv1);
    hipLaunchKernelGGL(k_posgates, dim3(NTOK / 16), dim3(256), 0, stream,
                       xT, pos_w, pos_b, n1w, n1b, gw, gb, feat, g, featb);
    hipLaunchKernelGGL(k_blkscore, dim3(BATCH * NB), dim3(256), 0, stream,
                       feat, s1w, s1b, s2w, s2b, blk, scores);
    // merged QKV projection (980 blocks) + kvcmp/kvsel fp32 GEMM (24 blocks)
    hipLaunchKernelGGL(k_qkvkv, dim3(1004), dim3(256), 0, stream,
                       featb, Wc1, bias1, bufQh,
                       blk, Wkv0, bkv0, kvcmp, scores, Wkv1, bkv1, kvsel);
    // all attention branches (16 tokens/block, f16 LDS-staged K/V) -> gated Acatb (bf16)
    hipLaunchKernelGGL(k_attn_lds, dim3(784), dim3(512), 0, stream,
                       bufQh, kvcmp, kvsel, Acatb, g);
    // fused output projection + residual + gated biases -> ym fp32 + ymb bf16  (392 blocks)
    hipLaunchKernelGGL(k_gemm64, dim3(CDIM / 64, NTOK / 64), dim3(256), 0, stream,
                       Acatb, Wpj, nullptr, ym, NTOK, CDIM, ASTR, feat, g, pj_b, ymb);
    // DBFFN: pin (row-permuted W) -> T1h f16 (channel-interleaved)  (784 blocks)
    hipLaunchKernelGGL(k_gemm64x128, dim3(HID2 / 128, NTOK / 64), dim3(256), 0, stream,
                       ymb, Wpin, nullptr, NTOK, HID2, 256, T1h);
    hipLaunchKernelGGL(k_dwglu2, dim3(BATCH * (HH / 2) * 8), dim3(256), 0, stream, T1h, dww, G);
    // fused pout GEMM + final LN + NCHW write
    hipLaunchKernelGGL(k_poutln, dim3(NTOK / 32), dim3(256), 0, stream,
                       G, Wpout, ym, n2w, n2b, out);
}